// Round 1
// baseline (3648.482 us; speedup 1.0000x reference)
//
#include <hip/hip_runtime.h>
#include <math.h>

#define B_  2
#define S_  2048
#define L_  2
#define E_  768
#define H_  12
#define D_  64
#define W_  256
#define FF_ 3072
#define NL_ 9

// ------------------------- reduction helpers -------------------------
__device__ __forceinline__ float waveAllSum(float v) {
  #pragma unroll
  for (int off = 1; off < 64; off <<= 1) v += __shfl_xor(v, off, 64);
  return v;
}
__device__ __forceinline__ float waveAllMax(float v) {
  #pragma unroll
  for (int off = 1; off < 64; off <<= 1) v = fmaxf(v, __shfl_xor(v, off, 64));
  return v;
}
template<int NW>
__device__ __forceinline__ float blockAllSum(float v, float* tmp, int t) {
  v = waveAllSum(v);
  __syncthreads();
  if ((t & 63) == 0) tmp[t >> 6] = v;
  __syncthreads();
  float r = 0.f;
  #pragma unroll
  for (int i = 0; i < NW; ++i) r += tmp[i];
  return r;
}
template<int NW>
__device__ __forceinline__ float blockAllMax(float v, float* tmp, int t) {
  v = waveAllMax(v);
  __syncthreads();
  if ((t & 63) == 0) tmp[t >> 6] = v;
  __syncthreads();
  float r = tmp[0];
  #pragma unroll
  for (int i = 1; i < NW; ++i) r = fmaxf(r, tmp[i]);
  return r;
}

// ------------------------- pos ids (cumsum) -------------------------
__global__ void pos_ids_kernel(const int* __restrict__ mask, int* __restrict__ pos) {
  __shared__ int part[256];
  int b = blockIdx.x, t = threadIdx.x;
  const int* mr = mask + b * S_;
  int* pr = pos + b * S_;
  int v[8]; int s = 0;
  #pragma unroll
  for (int j = 0; j < 8; ++j) { v[j] = mr[t * 8 + j]; s += v[j]; }
  part[t] = s;
  __syncthreads();
  for (int off = 1; off < 256; off <<= 1) {
    int add = (t >= off) ? part[t - off] : 0;
    __syncthreads();
    part[t] += add;
    __syncthreads();
  }
  int run = (t == 0) ? 0 : part[t - 1];   // exclusive prefix of this thread's chunk
  #pragma unroll
  for (int j = 0; j < 8; ++j) { run += v[j]; pr[t * 8 + j] = run * v[j] + 1; }
}

// ------------------------- embedding + LayerNorm -------------------------
__global__ __launch_bounds__(256) void embed_ln_kernel(
    const int* __restrict__ ids, const int* __restrict__ pos, const int* __restrict__ tti,
    const float* __restrict__ we, const float* __restrict__ pe, const float* __restrict__ te,
    const float* __restrict__ g, const float* __restrict__ bb, float* __restrict__ x) {
  __shared__ float tmp[4];
  int row = blockIdx.x, t = threadIdx.x;
  int id = ids[row], pid = pos[row], tt = tti[row];
  float v[3]; float s = 0.f;
  #pragma unroll
  for (int j = 0; j < 3; ++j) {
    int col = t + j * 256;
    v[j] = we[(size_t)id * E_ + col] + pe[(size_t)pid * E_ + col] + te[(size_t)tt * E_ + col];
    s += v[j];
  }
  float mean = blockAllSum<4>(s, tmp, t) * (1.f / E_);
  float ss = 0.f;
  #pragma unroll
  for (int j = 0; j < 3; ++j) { float d = v[j] - mean; ss += d * d; }
  float var = blockAllSum<4>(ss, tmp, t) * (1.f / E_);
  float rstd = rsqrtf(var + 1e-5f);
  float* op = x + (size_t)row * E_;
  #pragma unroll
  for (int j = 0; j < 3; ++j) {
    int col = t + j * 256;
    op[col] = (v[j] - mean) * rstd * g[col] + bb[col];
  }
}

// ------------------------- LayerNorm over rows of E -------------------------
__global__ __launch_bounds__(256) void ln_kernel(
    const float* __restrict__ in, const float* __restrict__ g,
    const float* __restrict__ bb, float* __restrict__ out) {
  __shared__ float tmp[4];
  int row = blockIdx.x, t = threadIdx.x;
  const float* ip = in + (size_t)row * E_;
  float v[3]; float s = 0.f;
  #pragma unroll
  for (int j = 0; j < 3; ++j) { v[j] = ip[t + j * 256]; s += v[j]; }
  float mean = blockAllSum<4>(s, tmp, t) * (1.f / E_);
  float ss = 0.f;
  #pragma unroll
  for (int j = 0; j < 3; ++j) { float d = v[j] - mean; ss += d * d; }
  float var = blockAllSum<4>(ss, tmp, t) * (1.f / E_);
  float rstd = rsqrtf(var + 1e-5f);
  float* op = out + (size_t)row * E_;
  #pragma unroll
  for (int j = 0; j < 3; ++j) {
    int col = t + j * 256;
    op[col] = (v[j] - mean) * rstd * g[col] + bb[col];
  }
}

// ------------------------- fp32 tiled GEMM -------------------------
// C[m,n] = sum_k A[m,k]*Bw[k,n] + bias[n]  (+epilogue)
// EPI: 0 = bias, 1 = bias+gelu(exact), 2 = bias+residual
#define BM 128
#define BN 64
#define BK 16
template<int EPI>
__global__ __launch_bounds__(256) void gemm_kernel(
    const float* __restrict__ A, const float* __restrict__ Bw,
    const float* __restrict__ bias, const float* __restrict__ res,
    float* __restrict__ C, int M, int N, int K, int ldb, int ldc) {
  __shared__ float As[BK][BM + 4];   // stride 132 floats (528B, 16B aligned)
  __shared__ float Bs[BK][BN];
  int t = threadIdx.x;
  int m0 = blockIdx.y * BM, n0 = blockIdx.x * BN;
  int tx = t & 15, ty = t >> 4;      // tx -> 4 cols, ty -> 8 rows
  float acc[8][4] = {};
  const int nkt = K / BK;
  for (int kt = 0; kt < nkt; ++kt) {
    int k0 = kt * BK;
    #pragma unroll
    for (int i = 0; i < 2; ++i) {          // A tile: 128x16
      int f = t * 2 + i;
      int row = f >> 2, kk = (f & 3) * 4;
      float4 av = *(const float4*)(A + (size_t)(m0 + row) * K + k0 + kk);
      As[kk + 0][row] = av.x; As[kk + 1][row] = av.y;
      As[kk + 2][row] = av.z; As[kk + 3][row] = av.w;
    }
    {                                       // B tile: 16x64
      int row = t >> 4, col = (t & 15) * 4;
      *(float4*)&Bs[row][col] = *(const float4*)(Bw + (size_t)(k0 + row) * ldb + n0 + col);
    }
    __syncthreads();
    #pragma unroll
    for (int kk = 0; kk < BK; ++kk) {
      float4 b4 = *(float4*)&Bs[kk][tx * 4];
      float4 a0 = *(float4*)&As[kk][ty * 8];
      float4 a1 = *(float4*)&As[kk][ty * 8 + 4];
      float am[8] = {a0.x, a0.y, a0.z, a0.w, a1.x, a1.y, a1.z, a1.w};
      float bv[4] = {b4.x, b4.y, b4.z, b4.w};
      #pragma unroll
      for (int i = 0; i < 8; ++i)
        #pragma unroll
        for (int j = 0; j < 4; ++j) acc[i][j] += am[i] * bv[j];
    }
    __syncthreads();
  }
  float bv[4];
  #pragma unroll
  for (int j = 0; j < 4; ++j) bv[j] = bias[n0 + tx * 4 + j];
  #pragma unroll
  for (int i = 0; i < 8; ++i) {
    int m = m0 + ty * 8 + i;
    float4 o;
    float* op = (float*)&o;
    #pragma unroll
    for (int j = 0; j < 4; ++j) {
      float v = acc[i][j] + bv[j];
      if (EPI == 1) v = 0.5f * v * (1.f + erff(v * 0.70710678118654752f));
      if (EPI == 2) v += res[(size_t)m * ldc + n0 + tx * 4 + j];
      op[j] = v;
    }
    *(float4*)(C + (size_t)m * ldc + n0 + tx * 4) = o;
  }
}

// ------------------------- local sliding-window attention -------------------------
// One thread per query; flash-style online softmax over 6 key tiles of 128
// plus the global column (key 0 via regular k/v) folded in as an extra key.
#define QB 128
__global__ __launch_bounds__(128) void attn_local_kernel(
    const float* __restrict__ qkv, const int* __restrict__ mask, float* __restrict__ aout) {
  __shared__ float Ks[128][64];
  __shared__ float Vs[128][64];
  __shared__ float k0s[64], v0s[64];
  __shared__ int Ms[128];
  int t = threadIdx.x;
  int c2 = blockIdx.x;                 // 128-query chunk, 0..15
  int h = blockIdx.y, b = blockIdx.z;
  int qpos = c2 * QB + t;
  int c = qpos >> 8;                   // 256-chunk index
  int kbase = c * 256 - 256;
  const float* base = qkv + (size_t)b * S_ * (3 * E_);
  if (t < 16) {
    *(float4*)&k0s[t * 4] = *(const float4*)(base + E_ + h * 64 + t * 4);
  } else if (t < 32) {
    int d = (t - 16) * 4;
    *(float4*)&v0s[d] = *(const float4*)(base + 2 * E_ + h * 64 + d);
  }
  float qv[64];
  {
    const float* qp = base + (size_t)qpos * (3 * E_) + h * 64;
    #pragma unroll
    for (int d4 = 0; d4 < 16; ++d4) {
      float4 q4 = *(const float4*)(qp + d4 * 4);
      qv[4 * d4 + 0] = q4.x * 0.125f; qv[4 * d4 + 1] = q4.y * 0.125f;
      qv[4 * d4 + 2] = q4.z * 0.125f; qv[4 * d4 + 3] = q4.w * 0.125f;
    }
  }
  float m = -3.0e38f, l = 0.f;
  float acc[64] = {};
  __syncthreads();
  if (mask[b * S_] == 1) {             // global column = extra key (k0,v0)
    float s = 0.f;
    #pragma unroll
    for (int d = 0; d < 64; ++d) s += qv[d] * k0s[d];
    m = s; l = 1.f;
    #pragma unroll
    for (int d = 0; d < 64; ++d) acc[d] = v0s[d];
  }
  #pragma unroll 1
  for (int tile = 0; tile < 6; ++tile) {
    __syncthreads();
    int r0 = kbase + tile * 128;
    #pragma unroll
    for (int i = 0; i < 8; ++i) {      // load K/V tile (zero-fill OOB)
      int f = i * 128 + t;
      int r = f >> 3;
      int dc = (f & 7) * 8;
      int kpos = r0 + r;
      float4 z = {0.f, 0.f, 0.f, 0.f};
      float4 k1 = z, k2 = z, v1 = z, v2 = z;
      bool inb = (kpos >= 0) && (kpos < S_);
      if (inb) {
        const float* kp = base + (size_t)kpos * (3 * E_) + E_ + h * 64 + dc;
        k1 = *(const float4*)kp; k2 = *(const float4*)(kp + 4);
        const float* vp = kp + E_;
        v1 = *(const float4*)vp; v2 = *(const float4*)(vp + 4);
      }
      *(float4*)&Ks[r][dc] = k1; *(float4*)&Ks[r][dc + 4] = k2;
      *(float4*)&Vs[r][dc] = v1; *(float4*)&Vs[r][dc + 4] = v2;
      if ((f & 7) == 0) Ms[r] = inb ? mask[b * S_ + kpos] : 0;
    }
    __syncthreads();
    #pragma unroll 1
    for (int sub = 0; sub < 8; ++sub) {
      float sc[16];
      #pragma unroll
      for (int j = 0; j < 16; ++j) {
        int kk = sub * 16 + j;
        const float4* kr = (const float4*)&Ks[kk][0];
        float s = 0.f;
        #pragma unroll
        for (int d4 = 0; d4 < 16; ++d4) {
          float4 kv = kr[d4];
          s += qv[4 * d4 + 0] * kv.x + qv[4 * d4 + 1] * kv.y
             + qv[4 * d4 + 2] * kv.z + qv[4 * d4 + 3] * kv.w;
        }
        int kpos = r0 + kk;
        int dd = kpos - qpos;
        bool ok = (dd <= W_) && (dd >= -W_) && (kpos > 0) && (kpos < S_) && (Ms[kk] == 1);
        sc[j] = ok ? s : -1e9f;
      }
      float tmax = sc[0];
      #pragma unroll
      for (int j = 1; j < 16; ++j) tmax = fmaxf(tmax, sc[j]);
      if (tmax > m) {
        float f = __expf(m - tmax);
        #pragma unroll
        for (int d = 0; d < 64; ++d) acc[d] *= f;
        l *= f; m = tmax;
      }
      #pragma unroll
      for (int j = 0; j < 16; ++j) {
        float e = __expf(sc[j] - m);
        l += e;
        const float4* vr = (const float4*)&Vs[sub * 16 + j][0];
        #pragma unroll
        for (int d4 = 0; d4 < 16; ++d4) {
          float4 vv = vr[d4];
          acc[4 * d4 + 0] += e * vv.x; acc[4 * d4 + 1] += e * vv.y;
          acc[4 * d4 + 2] += e * vv.z; acc[4 * d4 + 3] += e * vv.w;
        }
      }
    }
  }
  float inv = 1.f / l;
  float* op = aout + ((size_t)b * S_ + qpos) * E_ + h * 64;
  #pragma unroll
  for (int d4 = 0; d4 < 16; ++d4) {
    float4 o;
    o.x = acc[4 * d4 + 0] * inv; o.y = acc[4 * d4 + 1] * inv;
    o.z = acc[4 * d4 + 2] * inv; o.w = acc[4 * d4 + 3] * inv;
    *(float4*)(op + d4 * 4) = o;
  }
}

// ------------------------- global attention for token 0 -------------------------
__global__ __launch_bounds__(256) void attn_global_kernel(
    const float* __restrict__ qg0, const float* __restrict__ gkv,
    const int* __restrict__ mask, float* __restrict__ aout) {
  __shared__ float qs[64];
  __shared__ float probs[S_];
  __shared__ float tmp[4];
  __shared__ float pacc[256];
  int h = blockIdx.x, b = blockIdx.y;
  int t = threadIdx.x;
  if (t < 16) *(float4*)&qs[t * 4] = *(const float4*)(qg0 + b * E_ + h * 64 + t * 4);
  __syncthreads();
  float sv[8];
  float lmax = -3.0e38f;
  #pragma unroll
  for (int i = 0; i < 8; ++i) {
    int s = i * 256 + t;
    const float* kr = gkv + ((size_t)b * S_ + s) * 1536 + h * 64;
    float sum = 0.f;
    #pragma unroll
    for (int d = 0; d < 64; ++d) sum += qs[d] * kr[d];
    sv[i] = (mask[b * S_ + s] == 1) ? sum : -1e9f;
    lmax = fmaxf(lmax, sv[i]);
  }
  float gmax = blockAllMax<4>(lmax, tmp, t);
  float lsum = 0.f;
  #pragma unroll
  for (int i = 0; i < 8; ++i) {
    float e = __expf(sv[i] - gmax);
    probs[i * 256 + t] = e;
    lsum += e;
  }
  float gsum = blockAllSum<4>(lsum, tmp, t);
  float inv = 1.f / gsum;
  __syncthreads();
  int d = t & 63, grp = t >> 6;
  float accd = 0.f;
  for (int i = 0; i < 512; ++i) {
    int s = grp * 512 + i;
    accd += probs[s] * gkv[((size_t)b * S_ + s) * 1536 + 768 + h * 64 + d];
  }
  pacc[t] = accd;
  __syncthreads();
  if (t < 64) {
    float o = (pacc[t] + pacc[t + 64] + pacc[t + 128] + pacc[t + 192]) * inv;
    aout[((size_t)b * S_) * E_ + h * 64 + t] = o;
  }
}

// ------------------------- qg0 = x[:,0] @ Wg[:, :E] + bg[:E], scaled -------------------------
__global__ void qg0_kernel(const float* __restrict__ x, const float* __restrict__ Wg,
                           const float* __restrict__ bg, float* __restrict__ qg0) {
  int n = blockIdx.x * 256 + threadIdx.x;   // 0..767
  int b = blockIdx.y;
  const float* xr = x + (size_t)b * S_ * E_;
  float acc = bg[n];
  for (int k = 0; k < E_; ++k) acc += xr[k] * Wg[(size_t)k * (3 * E_) + n];
  qg0[b * E_ + n] = acc * 0.125f;
}

// ------------------------- classification head -------------------------
__global__ void cls_kernel(const float* __restrict__ x, const float* __restrict__ cw,
                           const float* __restrict__ cb, float* __restrict__ cls) {
  int n = blockIdx.x * 256 + threadIdx.x;
  int b = blockIdx.y;
  const float* xr = x + (size_t)b * S_ * E_;
  float acc = cb[n];
  for (int k = 0; k < E_; ++k) acc += xr[k] * cw[(size_t)k * E_ + n];
  cls[b * E_ + n] = tanhf(acc);
}

__global__ void out_kernel(const float* __restrict__ cls, const float* __restrict__ ow,
                           const float* __restrict__ ob, float* __restrict__ out) {
  int t = threadIdx.x;
  if (t < B_ * NL_) {
    int b = t / NL_, n = t % NL_;
    float acc = ob[n];
    for (int k = 0; k < E_; ++k) acc += cls[b * E_ + k] * ow[(size_t)k * NL_ + n];
    out[t] = acc;
  }
}

// ------------------------- launch -------------------------
extern "C" void kernel_launch(void* const* d_in, const int* in_sizes, int n_in,
                              void* d_out, int out_size, void* d_ws, size_t ws_size,
                              hipStream_t stream) {
  const int* ids   = (const int*)d_in[0];
  const int* mask  = (const int*)d_in[1];
  const int* tti   = (const int*)d_in[2];
  const float* we  = (const float*)d_in[3];
  const float* pe  = (const float*)d_in[4];
  const float* te  = (const float*)d_in[5];
  const float* lng = (const float*)d_in[6];
  const float* lnb = (const float*)d_in[7];
  const float* Wqkv = (const float*)d_in[8];
  const float* bqkv = (const float*)d_in[9];
  const float* Wg   = (const float*)d_in[10];
  const float* bg   = (const float*)d_in[11];
  const float* Wo   = (const float*)d_in[12];
  const float* bo   = (const float*)d_in[13];
  const float* ln1g = (const float*)d_in[14];
  const float* ln1b = (const float*)d_in[15];
  const float* Wi   = (const float*)d_in[16];
  const float* bi   = (const float*)d_in[17];
  const float* Wf   = (const float*)d_in[18];
  const float* bf_  = (const float*)d_in[19];
  const float* ln2g = (const float*)d_in[20];
  const float* ln2b = (const float*)d_in[21];
  const float* cw   = (const float*)d_in[22];
  const float* cb   = (const float*)d_in[23];
  const float* ow   = (const float*)d_in[24];
  const float* ob   = (const float*)d_in[25];
  float* out = (float*)d_out;

  char* ws = (char*)d_ws;
  size_t off = 0;
  auto alloc = [&](size_t bytes) { void* p = ws + off; off += (bytes + 255) & ~(size_t)255; return p; };
  const size_t BSE = (size_t)B_ * S_ * E_;
  int*   pos  = (int*)alloc((size_t)B_ * S_ * 4);
  float* x    = (float*)alloc(BSE * 4);
  float* y    = (float*)alloc(BSE * 4);
  float* a    = (float*)alloc(BSE * 4);
  float* gkv  = (float*)alloc((size_t)B_ * S_ * 1536 * 4);
  float* qg0  = (float*)alloc((size_t)B_ * E_ * 4);
  float* cls  = (float*)alloc((size_t)B_ * E_ * 4);
  float* big  = (float*)alloc((size_t)B_ * S_ * FF_ * 4);  // qkv (attn phase) / h (ffn phase)
  float* qkv  = big;
  float* hbuf = big;

  const int M = B_ * S_;

  pos_ids_kernel<<<B_, 256, 0, stream>>>(mask, pos);
  embed_ln_kernel<<<M, 256, 0, stream>>>(ids, pos, tti, we, pe, te, lng, lnb, x);

  for (int l = 0; l < L_; ++l) {
    const float* Wqkv_l = Wqkv + (size_t)l * E_ * 3 * E_;
    const float* bqkv_l = bqkv + (size_t)l * 3 * E_;
    const float* Wg_l   = Wg + (size_t)l * E_ * 3 * E_;
    const float* bg_l   = bg + (size_t)l * 3 * E_;
    const float* Wo_l   = Wo + (size_t)l * E_ * E_;
    const float* bo_l   = bo + (size_t)l * E_;
    const float* Wi_l   = Wi + (size_t)l * E_ * FF_;
    const float* bi_l   = bi + (size_t)l * FF_;
    const float* Wf_l   = Wf + (size_t)l * FF_ * E_;
    const float* bf_l   = bf_ + (size_t)l * E_;

    // qkv projection: (4096 x 768) @ (768 x 2304)
    gemm_kernel<0><<<dim3(3 * E_ / BN, M / BM), 256, 0, stream>>>(
        x, Wqkv_l, bqkv_l, nullptr, qkv, M, 3 * E_, E_, 3 * E_, 3 * E_);
    // global k,v projection: columns [E, 3E) of Wg
    gemm_kernel<0><<<dim3(2 * E_ / BN, M / BM), 256, 0, stream>>>(
        x, Wg_l + E_, bg_l + E_, nullptr, gkv, M, 2 * E_, E_, 3 * E_, 2 * E_);
    qg0_kernel<<<dim3(E_ / 256, B_), 256, 0, stream>>>(x, Wg_l, bg_l, qg0);

    attn_local_kernel<<<dim3(S_ / QB, H_, B_), QB, 0, stream>>>(qkv, mask, a);
    attn_global_kernel<<<dim3(H_, B_), 256, 0, stream>>>(qg0, gkv, mask, a);

    // out projection + residual, then LN
    gemm_kernel<2><<<dim3(E_ / BN, M / BM), 256, 0, stream>>>(
        a, Wo_l, bo_l, x, y, M, E_, E_, E_, E_);
    ln_kernel<<<M, 256, 0, stream>>>(y, ln1g + (size_t)l * E_, ln1b + (size_t)l * E_, x);

    // FFN
    gemm_kernel<1><<<dim3(FF_ / BN, M / BM), 256, 0, stream>>>(
        x, Wi_l, bi_l, nullptr, hbuf, M, FF_, E_, FF_, FF_);
    gemm_kernel<2><<<dim3(E_ / BN, M / BM), 256, 0, stream>>>(
        hbuf, Wf_l, bf_l, x, y, M, E_, FF_, E_, E_);
    ln_kernel<<<M, 256, 0, stream>>>(y, ln2g + (size_t)l * E_, ln2b + (size_t)l * E_, x);
  }

  cls_kernel<<<dim3(E_ / 256, B_), 256, 0, stream>>>(x, cw, cb, cls);
  out_kernel<<<1, 64, 0, stream>>>(cls, ow, ob, out);
}

// Round 4
// 1551.887 us; speedup vs baseline: 2.3510x; 2.3510x over previous
//
#include <hip/hip_runtime.h>
#include <hip/hip_bf16.h>
#include <math.h>

#define B_  2
#define S_  2048
#define L_  2
#define E_  768
#define H_  12
#define D_  64
#define W_  256
#define FF_ 3072
#define NL_ 9

typedef __attribute__((ext_vector_type(8))) short bf16x8;
typedef __attribute__((ext_vector_type(8))) unsigned short u16x8;
typedef __attribute__((ext_vector_type(4))) float f32x4;

__device__ __forceinline__ ushort f2bf(float f) {
  __hip_bfloat16 h = __float2bfloat16(f);
  return *(ushort*)&h;
}
__device__ __forceinline__ float bf2f(ushort u) {
  union { unsigned int i; float f; } c;
  c.i = ((unsigned int)u) << 16;
  return c.f;
}

__device__ __forceinline__ void gload_lds16(const void* g, void* l) {
  __builtin_amdgcn_global_load_lds(
      (const __attribute__((address_space(1))) void*)g,
      (__attribute__((address_space(3))) void*)l, 16, 0, 0);
}

// ------------------------- reduction helpers -------------------------
__device__ __forceinline__ float waveAllSum(float v) {
  #pragma unroll
  for (int off = 1; off < 64; off <<= 1) v += __shfl_xor(v, off, 64);
  return v;
}
__device__ __forceinline__ float waveAllMax(float v) {
  #pragma unroll
  for (int off = 1; off < 64; off <<= 1) v = fmaxf(v, __shfl_xor(v, off, 64));
  return v;
}
template<int NW>
__device__ __forceinline__ float blockAllSum(float v, float* tmp, int t) {
  v = waveAllSum(v);
  __syncthreads();
  if ((t & 63) == 0) tmp[t >> 6] = v;
  __syncthreads();
  float r = 0.f;
  #pragma unroll
  for (int i = 0; i < NW; ++i) r += tmp[i];
  return r;
}
template<int NW>
__device__ __forceinline__ float blockAllMax(float v, float* tmp, int t) {
  v = waveAllMax(v);
  __syncthreads();
  if ((t & 63) == 0) tmp[t >> 6] = v;
  __syncthreads();
  float r = tmp[0];
  #pragma unroll
  for (int i = 1; i < NW; ++i) r = fmaxf(r, tmp[i]);
  return r;
}

// ------------------------- pos ids (cumsum) -------------------------
__global__ void pos_ids_kernel(const int* __restrict__ mask, int* __restrict__ pos) {
  __shared__ int part[256];
  int b = blockIdx.x, t = threadIdx.x;
  const int* mr = mask + b * S_;
  int* pr = pos + b * S_;
  int v[8]; int s = 0;
  #pragma unroll
  for (int j = 0; j < 8; ++j) { v[j] = mr[t * 8 + j]; s += v[j]; }
  part[t] = s;
  __syncthreads();
  for (int off = 1; off < 256; off <<= 1) {
    int add = (t >= off) ? part[t - off] : 0;
    __syncthreads();
    part[t] += add;
    __syncthreads();
  }
  int run = (t == 0) ? 0 : part[t - 1];
  #pragma unroll
  for (int j = 0; j < 8; ++j) { run += v[j]; pr[t * 8 + j] = run * v[j] + 1; }
}

// ------------------------- embedding + LayerNorm (fp32 x + bf16 xb) ------------
__global__ __launch_bounds__(256) void embed_ln_kernel(
    const int* __restrict__ ids, const int* __restrict__ pos, const int* __restrict__ tti,
    const float* __restrict__ we, const float* __restrict__ pe, const float* __restrict__ te,
    const float* __restrict__ g, const float* __restrict__ bb,
    float* __restrict__ x, ushort* __restrict__ xb) {
  __shared__ float tmp[4];
  int row = blockIdx.x, t = threadIdx.x;
  int id = ids[row], pid = pos[row], tt = tti[row];
  float v[3]; float s = 0.f;
  #pragma unroll
  for (int j = 0; j < 3; ++j) {
    int col = t + j * 256;
    v[j] = we[(size_t)id * E_ + col] + pe[(size_t)pid * E_ + col] + te[(size_t)tt * E_ + col];
    s += v[j];
  }
  float mean = blockAllSum<4>(s, tmp, t) * (1.f / E_);
  float ss = 0.f;
  #pragma unroll
  for (int j = 0; j < 3; ++j) { float d = v[j] - mean; ss += d * d; }
  float var = blockAllSum<4>(ss, tmp, t) * (1.f / E_);
  float rstd = rsqrtf(var + 1e-5f);
  float* op = x + (size_t)row * E_;
  ushort* ob = xb + (size_t)row * E_;
  #pragma unroll
  for (int j = 0; j < 3; ++j) {
    int col = t + j * 256;
    float o = (v[j] - mean) * rstd * g[col] + bb[col];
    op[col] = o;
    ob[col] = f2bf(o);
  }
}

// ------------------------- LayerNorm (fp32 in -> fp32 x + bf16 xb) -------------
__global__ __launch_bounds__(256) void ln_kernel(
    const float* __restrict__ in, const float* __restrict__ g,
    const float* __restrict__ bb, float* __restrict__ out, ushort* __restrict__ outb) {
  __shared__ float tmp[4];
  int row = blockIdx.x, t = threadIdx.x;
  const float* ip = in + (size_t)row * E_;
  float v[3]; float s = 0.f;
  #pragma unroll
  for (int j = 0; j < 3; ++j) { v[j] = ip[t + j * 256]; s += v[j]; }
  float mean = blockAllSum<4>(s, tmp, t) * (1.f / E_);
  float ss = 0.f;
  #pragma unroll
  for (int j = 0; j < 3; ++j) { float d = v[j] - mean; ss += d * d; }
  float var = blockAllSum<4>(ss, tmp, t) * (1.f / E_);
  float rstd = rsqrtf(var + 1e-5f);
  float* op = out + (size_t)row * E_;
  ushort* ob = outb + (size_t)row * E_;
  #pragma unroll
  for (int j = 0; j < 3; ++j) {
    int col = t + j * 256;
    float o = (v[j] - mean) * rstd * g[col] + bb[col];
    op[col] = o;
    ob[col] = f2bf(o);
  }
}

// ------------------------- weight transpose + bf16 convert -------------------------
// src fp32 [K][N] row-major -> dst bf16 [N][K]
__global__ __launch_bounds__(256) void transposeW_kernel(
    const float* __restrict__ src, ushort* __restrict__ dst, int K, int N) {
  __shared__ float tile[32][33];
  int k0 = blockIdx.y * 32, n0 = blockIdx.x * 32;
  int t = threadIdx.x;
  #pragma unroll
  for (int i = 0; i < 4; ++i) {
    int idx = t + i * 256; int r = idx >> 5, cc = idx & 31;
    tile[r][cc] = src[(size_t)(k0 + r) * N + n0 + cc];
  }
  __syncthreads();
  #pragma unroll
  for (int i = 0; i < 4; ++i) {
    int idx = t + i * 256; int r = idx >> 5, cc = idx & 31;
    dst[(size_t)(n0 + r) * K + k0 + cc] = f2bf(tile[cc][r]);
  }
}

// ------------------------- bf16 MFMA GEMM -------------------------
// C[m,n] = A[m,:] . BT[n,:] + bias[n]   (A: [M][K] bf16, BT: [N][K] bf16)
// EPI 0: bias -> bf16 out; EPI 1: bias+gelu -> bf16 out; EPI 2: bias+res -> fp32 out
template<int EPI>
__global__ __launch_bounds__(256) void gemm_mfma(
    const ushort* __restrict__ A, const ushort* __restrict__ BT,
    const float* __restrict__ bias, const float* __restrict__ res,
    float* __restrict__ Cf, ushort* __restrict__ Cb, int M, int N, int K) {
  __shared__ __align__(16) ushort As[128 * 32];
  __shared__ __align__(16) ushort Bs[128 * 32];
  int t = threadIdx.x;
  int w = t >> 6, lane = t & 63;
  int wr = w >> 1, wc = w & 1;
  int fr = lane & 15, fg = lane >> 4;
  int m0 = blockIdx.y * 128, n0 = blockIdx.x * 128;
  f32x4 acc[4][4];
  #pragma unroll
  for (int m = 0; m < 4; ++m)
    #pragma unroll
    for (int n = 0; n < 4; ++n) acc[m][n] = (f32x4)0.f;

  int lrow = lane >> 2, lcol = (lane & 3) * 8;
  for (int k0 = 0; k0 < K; k0 += 32) {
    #pragma unroll
    for (int j = 0; j < 2; ++j) {
      int rbase = w * 32 + j * 16;
      gload_lds16(A + (size_t)(m0 + rbase + lrow) * K + k0 + lcol,
                  (void*)(As + rbase * 32));
      gload_lds16(BT + (size_t)(n0 + rbase + lrow) * K + k0 + lcol,
                  (void*)(Bs + rbase * 32));
    }
    __syncthreads();
    bf16x8 af[4], bf[4];
    #pragma unroll
    for (int m = 0; m < 4; ++m)
      af[m] = *(const bf16x8*)(As + (wr * 64 + m * 16 + fr) * 32 + fg * 8);
    #pragma unroll
    for (int n = 0; n < 4; ++n)
      bf[n] = *(const bf16x8*)(Bs + (wc * 64 + n * 16 + fr) * 32 + fg * 8);
    #pragma unroll
    for (int m = 0; m < 4; ++m)
      #pragma unroll
      for (int n = 0; n < 4; ++n)
        acc[m][n] = __builtin_amdgcn_mfma_f32_16x16x32_bf16(af[m], bf[n], acc[m][n], 0, 0, 0);
    __syncthreads();
  }

  #pragma unroll
  for (int n = 0; n < 4; ++n) {
    int col = n0 + wc * 64 + n * 16 + fr;
    float bv = bias[col];
    #pragma unroll
    for (int m = 0; m < 4; ++m) {
      int rbase = m0 + wr * 64 + m * 16 + fg * 4;
      #pragma unroll
      for (int r = 0; r < 4; ++r) {
        int row = rbase + r;
        float v = acc[m][n][r] + bv;
        if (EPI == 0) {
          Cb[(size_t)row * N + col] = f2bf(v);
        } else if (EPI == 1) {
          v = 0.5f * v * (1.f + erff(v * 0.70710678118654752f));
          Cb[(size_t)row * N + col] = f2bf(v);
        } else {
          Cf[(size_t)row * N + col] = v + res[(size_t)row * N + col];
        }
      }
    }
  }
}

// ------------------------- local sliding-window attention -------------------------
// qkv is bf16 [B*S][2304]. 4 lanes per query (16 dims each); 64 queries / block;
// 12 key-tiles of 64 staged (fp32) in LDS; global key 0 folded in; bf16 output.
__global__ __launch_bounds__(256) void attn_local_kernel(
    const ushort* __restrict__ qkv, const int* __restrict__ mask, ushort* __restrict__ aout) {
  __shared__ float Ks[64][68];
  __shared__ float Vs[64][68];
  __shared__ float k0s[64], v0s[64];
  __shared__ int Ms[64];
  int t = threadIdx.x;
  int qb = blockIdx.x;                 // 64-query chunk, 0..31
  int h = blockIdx.y, b = blockIdx.z;
  int q = t >> 2, sub = t & 3;
  int qpos = qb * 64 + q;
  int c = qpos >> 8;
  int kbase = c * 256 - 256;
  const ushort* base = qkv + (size_t)b * S_ * 2304;
  if (t < 64) k0s[t] = bf2f(base[E_ + h * 64 + t]);
  else if (t < 128) v0s[t - 64] = bf2f(base[2 * E_ + h * 64 + (t - 64)]);
  float qv[16];
  {
    const ushort* qp = base + (size_t)qpos * 2304 + h * 64 + sub * 16;
    u16x8 q0 = *(const u16x8*)qp;
    u16x8 q1 = *(const u16x8*)(qp + 8);
    #pragma unroll
    for (int d = 0; d < 8; ++d) {
      qv[d] = bf2f(q0[d]) * 0.125f;
      qv[d + 8] = bf2f(q1[d]) * 0.125f;
    }
  }
  float m = -3.0e38f, l = 0.f;
  float acc[16] = {};
  __syncthreads();
  if (mask[b * S_] == 1) {             // global column = extra key
    float s = 0.f;
    #pragma unroll
    for (int d = 0; d < 16; ++d) s += qv[d] * k0s[sub * 16 + d];
    s += __shfl_xor(s, 1, 64);
    s += __shfl_xor(s, 2, 64);
    m = s; l = 1.f;
    #pragma unroll
    for (int d = 0; d < 16; ++d) acc[d] = v0s[sub * 16 + d];
  }
  #pragma unroll 1
  for (int tile = 0; tile < 12; ++tile) {
    __syncthreads();
    int r0 = kbase + tile * 64;
    {
      int kr = t >> 2, sg = t & 3;
      int kpos = r0 + kr;
      bool inb = (kpos >= 0) && (kpos < S_);
      float kf[16] = {}, vf[16] = {};
      if (inb) {
        const ushort* kp = base + (size_t)kpos * 2304 + E_ + h * 64 + sg * 16;
        u16x8 k0v = *(const u16x8*)kp;
        u16x8 k1v = *(const u16x8*)(kp + 8);
        const ushort* vp = kp + E_;
        u16x8 v0v = *(const u16x8*)vp;
        u16x8 v1v = *(const u16x8*)(vp + 8);
        #pragma unroll
        for (int d = 0; d < 8; ++d) {
          kf[d] = bf2f(k0v[d]); kf[d + 8] = bf2f(k1v[d]);
          vf[d] = bf2f(v0v[d]); vf[d + 8] = bf2f(v1v[d]);
        }
      }
      float* kd = &Ks[kr][sg * 16];
      float* vd = &Vs[kr][sg * 16];
      #pragma unroll
      for (int d4 = 0; d4 < 4; ++d4) {
        *(float4*)(kd + d4 * 4) = *(float4*)&kf[d4 * 4];
        *(float4*)(vd + d4 * 4) = *(float4*)&vf[d4 * 4];
      }
      if (sg == 0) Ms[kr] = inb ? mask[b * S_ + kpos] : 0;
    }
    __syncthreads();
    #pragma unroll 1
    for (int sc4 = 0; sc4 < 4; ++sc4) {
      float scv[16];
      #pragma unroll
      for (int j = 0; j < 16; ++j) {
        int kk = sc4 * 16 + j;
        const float4* kr4 = (const float4*)&Ks[kk][sub * 16];
        float s = 0.f;
        #pragma unroll
        for (int d4 = 0; d4 < 4; ++d4) {
          float4 kv = kr4[d4];
          s += qv[4 * d4 + 0] * kv.x + qv[4 * d4 + 1] * kv.y
             + qv[4 * d4 + 2] * kv.z + qv[4 * d4 + 3] * kv.w;
        }
        scv[j] = s;
      }
      #pragma unroll
      for (int j = 0; j < 16; ++j) {
        scv[j] += __shfl_xor(scv[j], 1, 64);
        scv[j] += __shfl_xor(scv[j], 2, 64);
      }
      #pragma unroll
      for (int j = 0; j < 16; ++j) {
        int kpos = r0 + sc4 * 16 + j;
        int dd = kpos - qpos;
        bool ok = (dd <= W_) && (dd >= -W_) && (kpos > 0) && (kpos < S_) && (Ms[sc4 * 16 + j] == 1);
        scv[j] = ok ? scv[j] : -1e9f;
      }
      float tmax = scv[0];
      #pragma unroll
      for (int j = 1; j < 16; ++j) tmax = fmaxf(tmax, scv[j]);
      if (tmax > m) {
        float f = __expf(m - tmax);
        #pragma unroll
        for (int d = 0; d < 16; ++d) acc[d] *= f;
        l *= f; m = tmax;
      }
      #pragma unroll
      for (int j = 0; j < 16; ++j) {
        float e = __expf(scv[j] - m);
        l += e;
        const float4* vr = (const float4*)&Vs[sc4 * 16 + j][sub * 16];
        #pragma unroll
        for (int d4 = 0; d4 < 4; ++d4) {
          float4 vv = vr[d4];
          acc[4 * d4 + 0] += e * vv.x; acc[4 * d4 + 1] += e * vv.y;
          acc[4 * d4 + 2] += e * vv.z; acc[4 * d4 + 3] += e * vv.w;
        }
      }
    }
  }
  float inv = 1.f / l;
  ushort* op = aout + ((size_t)b * S_ + qpos) * E_ + h * 64 + sub * 16;
  ushort o16[16];
  #pragma unroll
  for (int d = 0; d < 16; ++d) o16[d] = f2bf(acc[d] * inv);
  #pragma unroll
  for (int d4 = 0; d4 < 4; ++d4)
    *(ushort4*)(op + d4 * 4) = *(ushort4*)&o16[d4 * 4];
}

// ------------------------- global attention for token 0 -------------------------
// gkv is bf16 [B*S][1536] (k | v for the global projection).
__global__ __launch_bounds__(256) void attn_global_kernel(
    const float* __restrict__ qg0, const ushort* __restrict__ gkv,
    const int* __restrict__ mask, ushort* __restrict__ aout) {
  __shared__ float qs[64];
  __shared__ float probs[S_];
  __shared__ float tmp[4];
  __shared__ float pacc[256];
  int h = blockIdx.x, b = blockIdx.y;
  int t = threadIdx.x;
  if (t < 16) *(float4*)&qs[t * 4] = *(const float4*)(qg0 + b * E_ + h * 64 + t * 4);
  __syncthreads();
  float sv[8];
  float lmax = -3.0e38f;
  #pragma unroll
  for (int i = 0; i < 8; ++i) {
    int s = i * 256 + t;
    const ushort* kr = gkv + ((size_t)b * S_ + s) * 1536 + h * 64;
    float sum = 0.f;
    #pragma unroll
    for (int d = 0; d < 64; ++d) sum += qs[d] * bf2f(kr[d]);
    sv[i] = (mask[b * S_ + s] == 1) ? sum : -1e9f;
    lmax = fmaxf(lmax, sv[i]);
  }
  float gmax = blockAllMax<4>(lmax, tmp, t);
  float lsum = 0.f;
  #pragma unroll
  for (int i = 0; i < 8; ++i) {
    float e = __expf(sv[i] - gmax);
    probs[i * 256 + t] = e;
    lsum += e;
  }
  float gsum = blockAllSum<4>(lsum, tmp, t);
  float inv = 1.f / gsum;
  __syncthreads();
  int d = t & 63, grp = t >> 6;
  float accd = 0.f;
  for (int i = 0; i < 512; ++i) {
    int s = grp * 512 + i;
    accd += probs[s] * bf2f(gkv[((size_t)b * S_ + s) * 1536 + 768 + h * 64 + d]);
  }
  pacc[t] = accd;
  __syncthreads();
  if (t < 64) {
    float o = (pacc[t] + pacc[t + 64] + pacc[t + 128] + pacc[t + 192]) * inv;
    aout[((size_t)b * S_) * E_ + h * 64 + t] = f2bf(o);
  }
}

// ------------------------- qg0 = x[:,0] @ Wg[:, :E] + bg[:E], scaled ----------
__global__ void qg0_kernel(const float* __restrict__ x, const float* __restrict__ Wg,
                           const float* __restrict__ bg, float* __restrict__ qg0) {
  int n = blockIdx.x * 256 + threadIdx.x;
  int b = blockIdx.y;
  const float* xr = x + (size_t)b * S_ * E_;
  float acc = bg[n];
  for (int k = 0; k < E_; ++k) acc += xr[k] * Wg[(size_t)k * (3 * E_) + n];
  qg0[b * E_ + n] = acc * 0.125f;
}

// ------------------------- classification head -------------------------
__global__ void cls_kernel(const float* __restrict__ x, const float* __restrict__ cw,
                           const float* __restrict__ cb, float* __restrict__ cls) {
  int n = blockIdx.x * 256 + threadIdx.x;
  int b = blockIdx.y;
  const float* xr = x + (size_t)b * S_ * E_;
  float acc = cb[n];
  for (int k = 0; k < E_; ++k) acc += xr[k] * cw[(size_t)k * E_ + n];
  cls[b * E_ + n] = tanhf(acc);
}

__global__ void out_kernel(const float* __restrict__ cls, const float* __restrict__ ow,
                           const float* __restrict__ ob, float* __restrict__ out) {
  int t = threadIdx.x;
  if (t < B_ * NL_) {
    int b = t / NL_, n = t % NL_;
    float acc = ob[n];
    for (int k = 0; k < E_; ++k) acc += cls[b * E_ + k] * ow[(size_t)k * NL_ + n];
    out[t] = acc;
  }
}

// ------------------------- launch -------------------------
extern "C" void kernel_launch(void* const* d_in, const int* in_sizes, int n_in,
                              void* d_out, int out_size, void* d_ws, size_t ws_size,
                              hipStream_t stream) {
  const int* ids   = (const int*)d_in[0];
  const int* mask  = (const int*)d_in[1];
  const int* tti   = (const int*)d_in[2];
  const float* we  = (const float*)d_in[3];
  const float* pe  = (const float*)d_in[4];
  const float* te  = (const float*)d_in[5];
  const float* lng = (const float*)d_in[6];
  const float* lnb = (const float*)d_in[7];
  const float* Wqkv = (const float*)d_in[8];
  const float* bqkv = (const float*)d_in[9];
  const float* Wg   = (const float*)d_in[10];
  const float* bg   = (const float*)d_in[11];
  const float* Wo   = (const float*)d_in[12];
  const float* bo   = (const float*)d_in[13];
  const float* ln1g = (const float*)d_in[14];
  const float* ln1b = (const float*)d_in[15];
  const float* Wi   = (const float*)d_in[16];
  const float* bi   = (const float*)d_in[17];
  const float* Wf   = (const float*)d_in[18];
  const float* bf_  = (const float*)d_in[19];
  const float* ln2g = (const float*)d_in[20];
  const float* ln2b = (const float*)d_in[21];
  const float* cw   = (const float*)d_in[22];
  const float* cb   = (const float*)d_in[23];
  const float* ow   = (const float*)d_in[24];
  const float* ob   = (const float*)d_in[25];
  float* out = (float*)d_out;

  char* ws = (char*)d_ws;
  size_t off = 0;
  auto alloc = [&](size_t bytes) { void* p = ws + off; off += (bytes + 255) & ~(size_t)255; return p; };
  const size_t BSE = (size_t)B_ * S_ * E_;
  int*    pos  = (int*)alloc((size_t)B_ * S_ * 4);
  float*  x    = (float*)alloc(BSE * 4);
  float*  y    = (float*)alloc(BSE * 4);
  ushort* xb   = (ushort*)alloc(BSE * 2);
  ushort* ab   = (ushort*)alloc(BSE * 2);
  ushort* qkvb = (ushort*)alloc((size_t)B_ * S_ * 2304 * 2);   // bf16 qkv
  ushort* gkvb = (ushort*)alloc((size_t)B_ * S_ * 1536 * 2);   // bf16 global k|v
  float*  qg0  = (float*)alloc((size_t)B_ * E_ * 4);
  float*  cls  = (float*)alloc((size_t)B_ * E_ * 4);
  // per-layer transposed bf16 weights
  ushort* WqkvT = (ushort*)alloc((size_t)2304 * 768 * 2);
  ushort* WgT   = (ushort*)alloc((size_t)2304 * 768 * 2);
  ushort* WoT   = (ushort*)alloc((size_t)768 * 768 * 2);
  ushort* WiT   = (ushort*)alloc((size_t)3072 * 768 * 2);
  ushort* WfT   = (ushort*)alloc((size_t)768 * 3072 * 2);
  // FFN hidden (bf16, B*S*FF = 25.2MB) aliases the contiguous qkvb+gkvb
  // region (31.5MB) — both dead in the FFN phase.
  ushort* hb = qkvb;

  const int M = B_ * S_;

  pos_ids_kernel<<<B_, 256, 0, stream>>>(mask, pos);
  embed_ln_kernel<<<M, 256, 0, stream>>>(ids, pos, tti, we, pe, te, lng, lnb, x, xb);

  for (int l = 0; l < L_; ++l) {
    const float* Wqkv_l = Wqkv + (size_t)l * E_ * 3 * E_;
    const float* bqkv_l = bqkv + (size_t)l * 3 * E_;
    const float* Wg_l   = Wg + (size_t)l * E_ * 3 * E_;
    const float* bg_l   = bg + (size_t)l * 3 * E_;
    const float* Wo_l   = Wo + (size_t)l * E_ * E_;
    const float* bo_l   = bo + (size_t)l * E_;
    const float* Wi_l   = Wi + (size_t)l * E_ * FF_;
    const float* bi_l   = bi + (size_t)l * FF_;
    const float* Wf_l   = Wf + (size_t)l * FF_ * E_;
    const float* bf_l   = bf_ + (size_t)l * E_;

    transposeW_kernel<<<dim3(2304 / 32, 768 / 32), 256, 0, stream>>>(Wqkv_l, WqkvT, 768, 2304);
    transposeW_kernel<<<dim3(2304 / 32, 768 / 32), 256, 0, stream>>>(Wg_l, WgT, 768, 2304);
    transposeW_kernel<<<dim3(768 / 32, 768 / 32), 256, 0, stream>>>(Wo_l, WoT, 768, 768);
    transposeW_kernel<<<dim3(3072 / 32, 768 / 32), 256, 0, stream>>>(Wi_l, WiT, 768, 3072);
    transposeW_kernel<<<dim3(768 / 32, 3072 / 32), 256, 0, stream>>>(Wf_l, WfT, 3072, 768);

    // qkv = x @ Wqkv + b  (bf16 out)
    gemm_mfma<0><<<dim3(2304 / 128, M / 128), 256, 0, stream>>>(
        xb, WqkvT, bqkv_l, nullptr, nullptr, qkvb, M, 2304, 768);
    // gkv = x @ Wg[:, E:] + bg[E:]  (bf16 out)
    gemm_mfma<0><<<dim3(1536 / 128, M / 128), 256, 0, stream>>>(
        xb, WgT + (size_t)E_ * 768, bg_l + E_, nullptr, nullptr, gkvb, M, 1536, 768);
    qg0_kernel<<<dim3(E_ / 256, B_), 256, 0, stream>>>(x, Wg_l, bg_l, qg0);

    attn_local_kernel<<<dim3(S_ / 64, H_, B_), 256, 0, stream>>>(qkvb, mask, ab);
    attn_global_kernel<<<dim3(H_, B_), 256, 0, stream>>>(qg0, gkvb, mask, ab);

    // y = a @ Wo + bo + x ; x = LN(y)
    gemm_mfma<2><<<dim3(768 / 128, M / 128), 256, 0, stream>>>(
        ab, WoT, bo_l, x, y, nullptr, M, 768, 768);
    ln_kernel<<<M, 256, 0, stream>>>(y, ln1g + (size_t)l * E_, ln1b + (size_t)l * E_, x, xb);

    // h = gelu(x @ Wi + bi) (bf16) ; y = h @ Wf + bf + x ; x = LN(y)
    gemm_mfma<1><<<dim3(3072 / 128, M / 128), 256, 0, stream>>>(
        xb, WiT, bi_l, nullptr, nullptr, hb, M, 3072, 768);
    gemm_mfma<2><<<dim3(768 / 128, M / 128), 256, 0, stream>>>(
        hb, WfT, bf_l, x, y, nullptr, M, 768, 3072);
    ln_kernel<<<M, 256, 0, stream>>>(y, ln2g + (size_t)l * E_, ln2b + (size_t)l * E_, x, xb);
  }

  cls_kernel<<<dim3(E_ / 256, B_), 256, 0, stream>>>(x, cw, cb, cls);
  out_kernel<<<1, 64, 0, stream>>>(cls, ow, ob, out);
}

// Round 5
// 1142.577 us; speedup vs baseline: 3.1932x; 1.3582x over previous
//
#include <hip/hip_runtime.h>
#include <hip/hip_bf16.h>
#include <math.h>

#define B_  2
#define S_  2048
#define L_  2
#define E_  768
#define H_  12
#define D_  64
#define W_  256
#define FF_ 3072
#define NL_ 9

typedef __attribute__((ext_vector_type(8))) short bf16x8;
typedef __attribute__((ext_vector_type(8))) unsigned short u16x8;
typedef __attribute__((ext_vector_type(4))) float f32x4;

__device__ __forceinline__ ushort f2bf(float f) {
  __hip_bfloat16 h = __float2bfloat16(f);
  return *(ushort*)&h;
}
__device__ __forceinline__ float bf2f(ushort u) {
  union { unsigned int i; float f; } c;
  c.i = ((unsigned int)u) << 16;
  return c.f;
}

__device__ __forceinline__ void gload_lds16(const void* g, void* l) {
  __builtin_amdgcn_global_load_lds(
      (const __attribute__((address_space(1))) void*)g,
      (__attribute__((address_space(3))) void*)l, 16, 0, 0);
}

// ------------------------- reduction helpers -------------------------
__device__ __forceinline__ float waveAllSum(float v) {
  #pragma unroll
  for (int off = 1; off < 64; off <<= 1) v += __shfl_xor(v, off, 64);
  return v;
}
__device__ __forceinline__ float waveAllMax(float v) {
  #pragma unroll
  for (int off = 1; off < 64; off <<= 1) v = fmaxf(v, __shfl_xor(v, off, 64));
  return v;
}
template<int NW>
__device__ __forceinline__ float blockAllSum(float v, float* tmp, int t) {
  v = waveAllSum(v);
  __syncthreads();
  if ((t & 63) == 0) tmp[t >> 6] = v;
  __syncthreads();
  float r = 0.f;
  #pragma unroll
  for (int i = 0; i < NW; ++i) r += tmp[i];
  return r;
}
template<int NW>
__device__ __forceinline__ float blockAllMax(float v, float* tmp, int t) {
  v = waveAllMax(v);
  __syncthreads();
  if ((t & 63) == 0) tmp[t >> 6] = v;
  __syncthreads();
  float r = tmp[0];
  #pragma unroll
  for (int i = 1; i < NW; ++i) r = fmaxf(r, tmp[i]);
  return r;
}

// ------------------------- pos ids (cumsum) -------------------------
__global__ void pos_ids_kernel(const int* __restrict__ mask, int* __restrict__ pos) {
  __shared__ int part[256];
  int b = blockIdx.x, t = threadIdx.x;
  const int* mr = mask + b * S_;
  int* pr = pos + b * S_;
  int v[8]; int s = 0;
  #pragma unroll
  for (int j = 0; j < 8; ++j) { v[j] = mr[t * 8 + j]; s += v[j]; }
  part[t] = s;
  __syncthreads();
  for (int off = 1; off < 256; off <<= 1) {
    int add = (t >= off) ? part[t - off] : 0;
    __syncthreads();
    part[t] += add;
    __syncthreads();
  }
  int run = (t == 0) ? 0 : part[t - 1];
  #pragma unroll
  for (int j = 0; j < 8; ++j) { run += v[j]; pr[t * 8 + j] = run * v[j] + 1; }
}

// ------------------------- embedding + LayerNorm (fp32 x + bf16 xb) ------------
__global__ __launch_bounds__(256) void embed_ln_kernel(
    const int* __restrict__ ids, const int* __restrict__ pos, const int* __restrict__ tti,
    const float* __restrict__ we, const float* __restrict__ pe, const float* __restrict__ te,
    const float* __restrict__ g, const float* __restrict__ bb,
    float* __restrict__ x, ushort* __restrict__ xb) {
  __shared__ float tmp[4];
  int row = blockIdx.x, t = threadIdx.x;
  int id = ids[row], pid = pos[row], tt = tti[row];
  float v[3]; float s = 0.f;
  #pragma unroll
  for (int j = 0; j < 3; ++j) {
    int col = t + j * 256;
    v[j] = we[(size_t)id * E_ + col] + pe[(size_t)pid * E_ + col] + te[(size_t)tt * E_ + col];
    s += v[j];
  }
  float mean = blockAllSum<4>(s, tmp, t) * (1.f / E_);
  float ss = 0.f;
  #pragma unroll
  for (int j = 0; j < 3; ++j) { float d = v[j] - mean; ss += d * d; }
  float var = blockAllSum<4>(ss, tmp, t) * (1.f / E_);
  float rstd = rsqrtf(var + 1e-5f);
  float* op = x + (size_t)row * E_;
  ushort* ob = xb + (size_t)row * E_;
  #pragma unroll
  for (int j = 0; j < 3; ++j) {
    int col = t + j * 256;
    float o = (v[j] - mean) * rstd * g[col] + bb[col];
    op[col] = o;
    ob[col] = f2bf(o);
  }
}

// ------------------------- LayerNorm (fp32 in -> fp32 x + bf16 xb) -------------
__global__ __launch_bounds__(256) void ln_kernel(
    const float* __restrict__ in, const float* __restrict__ g,
    const float* __restrict__ bb, float* __restrict__ out, ushort* __restrict__ outb) {
  __shared__ float tmp[4];
  int row = blockIdx.x, t = threadIdx.x;
  const float* ip = in + (size_t)row * E_;
  float v[3]; float s = 0.f;
  #pragma unroll
  for (int j = 0; j < 3; ++j) { v[j] = ip[t + j * 256]; s += v[j]; }
  float mean = blockAllSum<4>(s, tmp, t) * (1.f / E_);
  float ss = 0.f;
  #pragma unroll
  for (int j = 0; j < 3; ++j) { float d = v[j] - mean; ss += d * d; }
  float var = blockAllSum<4>(ss, tmp, t) * (1.f / E_);
  float rstd = rsqrtf(var + 1e-5f);
  float* op = out + (size_t)row * E_;
  ushort* ob = outb + (size_t)row * E_;
  #pragma unroll
  for (int j = 0; j < 3; ++j) {
    int col = t + j * 256;
    float o = (v[j] - mean) * rstd * g[col] + bb[col];
    op[col] = o;
    ob[col] = f2bf(o);
  }
}

// ------------------------- weight transpose + bf16 convert -------------------------
// src fp32 [K][N] row-major -> dst bf16 [N][K]
__global__ __launch_bounds__(256) void transposeW_kernel(
    const float* __restrict__ src, ushort* __restrict__ dst, int K, int N) {
  __shared__ float tile[32][33];
  int k0 = blockIdx.y * 32, n0 = blockIdx.x * 32;
  int t = threadIdx.x;
  #pragma unroll
  for (int i = 0; i < 4; ++i) {
    int idx = t + i * 256; int r = idx >> 5, cc = idx & 31;
    tile[r][cc] = src[(size_t)(k0 + r) * N + n0 + cc];
  }
  __syncthreads();
  #pragma unroll
  for (int i = 0; i < 4; ++i) {
    int idx = t + i * 256; int r = idx >> 5, cc = idx & 31;
    dst[(size_t)(n0 + r) * K + k0 + cc] = f2bf(tile[cc][r]);
  }
}

// ------------------------- bf16 MFMA GEMM -------------------------
// C[m,n] = A[m,:] . BT[n,:] + bias[n]   (A: [M][K] bf16, BT: [N][K] bf16)
// EPI 0: bias -> bf16 out; EPI 1: bias+gelu -> bf16 out; EPI 2: bias+res -> fp32 out
template<int EPI>
__global__ __launch_bounds__(256) void gemm_mfma(
    const ushort* __restrict__ A, const ushort* __restrict__ BT,
    const float* __restrict__ bias, const float* __restrict__ res,
    float* __restrict__ Cf, ushort* __restrict__ Cb, int M, int N, int K) {
  __shared__ __align__(16) ushort As[128 * 32];
  __shared__ __align__(16) ushort Bs[128 * 32];
  int t = threadIdx.x;
  int w = t >> 6, lane = t & 63;
  int wr = w >> 1, wc = w & 1;
  int fr = lane & 15, fg = lane >> 4;
  int m0 = blockIdx.y * 128, n0 = blockIdx.x * 128;
  f32x4 acc[4][4];
  #pragma unroll
  for (int m = 0; m < 4; ++m)
    #pragma unroll
    for (int n = 0; n < 4; ++n) acc[m][n] = (f32x4)0.f;

  int lrow = lane >> 2, lcol = (lane & 3) * 8;
  for (int k0 = 0; k0 < K; k0 += 32) {
    #pragma unroll
    for (int j = 0; j < 2; ++j) {
      int rbase = w * 32 + j * 16;
      gload_lds16(A + (size_t)(m0 + rbase + lrow) * K + k0 + lcol,
                  (void*)(As + rbase * 32));
      gload_lds16(BT + (size_t)(n0 + rbase + lrow) * K + k0 + lcol,
                  (void*)(Bs + rbase * 32));
    }
    __syncthreads();
    bf16x8 af[4], bf[4];
    #pragma unroll
    for (int m = 0; m < 4; ++m)
      af[m] = *(const bf16x8*)(As + (wr * 64 + m * 16 + fr) * 32 + fg * 8);
    #pragma unroll
    for (int n = 0; n < 4; ++n)
      bf[n] = *(const bf16x8*)(Bs + (wc * 64 + n * 16 + fr) * 32 + fg * 8);
    #pragma unroll
    for (int m = 0; m < 4; ++m)
      #pragma unroll
      for (int n = 0; n < 4; ++n)
        acc[m][n] = __builtin_amdgcn_mfma_f32_16x16x32_bf16(af[m], bf[n], acc[m][n], 0, 0, 0);
    __syncthreads();
  }

  #pragma unroll
  for (int n = 0; n < 4; ++n) {
    int col = n0 + wc * 64 + n * 16 + fr;
    float bv = bias[col];
    #pragma unroll
    for (int m = 0; m < 4; ++m) {
      int rbase = m0 + wr * 64 + m * 16 + fg * 4;
      #pragma unroll
      for (int r = 0; r < 4; ++r) {
        int row = rbase + r;
        float v = acc[m][n][r] + bv;
        if (EPI == 0) {
          Cb[(size_t)row * N + col] = f2bf(v);
        } else if (EPI == 1) {
          v = 0.5f * v * (1.f + erff(v * 0.70710678118654752f));
          Cb[(size_t)row * N + col] = f2bf(v);
        } else {
          Cf[(size_t)row * N + col] = v + res[(size_t)row * N + col];
        }
      }
    }
  }
}

// ------------------------- local sliding-window attention (MFMA) ----------------
// One block = 256 threads (4 waves) = 64 queries of one (b,h). Each wave owns 16
// queries. 12 key-tiles of 64: K staged [key][72] bf16, V staged transposed
// [d][72] bf16. Scores via mfma(Q, K^T-layout), P transposed through per-wave
// LDS, PV via mfma(P, V^T-layout). Online softmax fp32. Global key 0 in init.
#define PADK 72
__global__ __launch_bounds__(256) void attn_local_kernel(
    const ushort* __restrict__ qkv, const int* __restrict__ mask, ushort* __restrict__ aout) {
  __shared__ __align__(16) ushort Kb[64 * PADK];
  __shared__ __align__(16) ushort Vt[64 * PADK];
  __shared__ __align__(16) ushort Pl[4][16 * PADK];
  __shared__ float k0s[64], v0s[64];
  __shared__ float pen[64];
  int t = threadIdx.x;
  int w = t >> 6, lane = t & 63;
  int fr = lane & 15, fg = lane >> 4;
  int qb0 = blockIdx.x * 64;
  int h = blockIdx.y, b = blockIdx.z;
  int kbase = ((qb0 >> 8) << 8) - 256;
  const ushort* base = qkv + (size_t)b * S_ * 2304;

  if (t < 64) k0s[t] = bf2f(base[E_ + h * 64 + t]);
  else if (t < 128) v0s[t - 64] = bf2f(base[2 * E_ + h * 64 + (t - 64)]);
  int gmask = mask[b * S_];

  // Q A-fragments, pre-scaled by 1/8 (exact pow2 scale)
  int qrowA = qb0 + w * 16 + fr;
  bf16x8 afq[2];
  #pragma unroll
  for (int kk = 0; kk < 2; ++kk) {
    u16x8 qv = *(const u16x8*)(base + (size_t)qrowA * 2304 + h * 64 + kk * 32 + fg * 8);
    ushort o[8];
    #pragma unroll
    for (int j = 0; j < 8; ++j) o[j] = f2bf(bf2f(qv[j]) * 0.125f);
    afq[kk] = *(bf16x8*)o;
  }
  __syncthreads();

  // global key-0 score per A-row query, then redistribute to C-row order
  float s0 = 0.f;
  #pragma unroll
  for (int kk = 0; kk < 2; ++kk) {
    ushort* ap = (ushort*)&afq[kk];
    #pragma unroll
    for (int j = 0; j < 8; ++j) s0 += bf2f(ap[j]) * k0s[kk * 32 + fg * 8 + j];
  }
  s0 += __shfl_xor(s0, 16, 64);
  s0 += __shfl_xor(s0, 32, 64);

  float m_j[4], l_j[4];
  f32x4 oa[4];
  #pragma unroll
  for (int j = 0; j < 4; ++j) {
    float s0q = __shfl(s0, fg * 4 + j, 64);
    m_j[j] = gmask ? s0q : -3.0e38f;
    l_j[j] = (gmask && fr == 0) ? 1.f : 0.f;
  }
  #pragma unroll
  for (int dn = 0; dn < 4; ++dn) {
    float v0 = gmask ? v0s[dn * 16 + fr] : 0.f;
    oa[dn] = (f32x4){v0, v0, v0, v0};
  }

  #pragma unroll 1
  for (int tile = 0; tile < 12; ++tile) {
    int r0 = kbase + tile * 64;
    __syncthreads();
    {
      int r = t >> 2, sg = t & 3;
      int kpos = r0 + r;
      bool inb = (kpos >= 0) && (kpos < S_);
      u16x8 kv0 = (u16x8)0, kv1 = (u16x8)0, vv0 = (u16x8)0, vv1 = (u16x8)0;
      if (inb) {
        const ushort* kp = base + (size_t)kpos * 2304 + E_ + h * 64 + sg * 16;
        kv0 = *(const u16x8*)kp;
        kv1 = *(const u16x8*)(kp + 8);
        const ushort* vp = kp + E_;
        vv0 = *(const u16x8*)vp;
        vv1 = *(const u16x8*)(vp + 8);
      }
      *(u16x8*)(Kb + r * PADK + sg * 16) = kv0;
      *(u16x8*)(Kb + r * PADK + sg * 16 + 8) = kv1;
      #pragma unroll
      for (int dd = 0; dd < 8; ++dd) Vt[(sg * 16 + dd) * PADK + r] = vv0[dd];
      #pragma unroll
      for (int dd = 0; dd < 8; ++dd) Vt[(sg * 16 + 8 + dd) * PADK + r] = vv1[dd];
      if (sg == 0) pen[r] = (inb && kpos != 0 && mask[b * S_ + kpos] == 1) ? 0.f : -1e9f;
    }
    __syncthreads();

    // scores: 16q x 64k
    f32x4 sc[4];
    #pragma unroll
    for (int kn = 0; kn < 4; ++kn) {
      bf16x8 bk0 = *(const bf16x8*)(Kb + (kn * 16 + fr) * PADK + fg * 8);
      bf16x8 bk1 = *(const bf16x8*)(Kb + (kn * 16 + fr) * PADK + 32 + fg * 8);
      f32x4 s = (f32x4)0.f;
      s = __builtin_amdgcn_mfma_f32_16x16x32_bf16(afq[0], bk0, s, 0, 0, 0);
      s = __builtin_amdgcn_mfma_f32_16x16x32_bf16(afq[1], bk1, s, 0, 0, 0);
      sc[kn] = s;
    }
    // masking: C elem (q = qb0 + w*16 + fg*4 + j, k = r0 + kn*16 + fr)
    int qrowC = qb0 + w * 16 + fg * 4;
    #pragma unroll
    for (int kn = 0; kn < 4; ++kn) {
      int kpos = r0 + kn * 16 + fr;
      float pn = pen[kn * 16 + fr];
      #pragma unroll
      for (int j = 0; j < 4; ++j) {
        int dd = kpos - (qrowC + j);
        bool okr = (dd <= W_) && (dd >= -W_);
        sc[kn][j] = okr ? (sc[kn][j] + pn) : -1e9f;
      }
    }
    // online softmax update (row = query, reduce across fr lanes)
    float f_j[4];
    #pragma unroll
    for (int j = 0; j < 4; ++j) {
      float tm = fmaxf(fmaxf(sc[0][j], sc[1][j]), fmaxf(sc[2][j], sc[3][j]));
      tm = fmaxf(tm, __shfl_xor(tm, 1, 64));
      tm = fmaxf(tm, __shfl_xor(tm, 2, 64));
      tm = fmaxf(tm, __shfl_xor(tm, 4, 64));
      tm = fmaxf(tm, __shfl_xor(tm, 8, 64));
      float mn = fmaxf(m_j[j], tm);
      float f = __expf(m_j[j] - mn);
      m_j[j] = mn;
      f_j[j] = f;
      l_j[j] *= f;
    }
    // P = exp(s - m), per-lane l partials, write P^T to per-wave LDS
    #pragma unroll
    for (int kn = 0; kn < 4; ++kn) {
      #pragma unroll
      for (int j = 0; j < 4; ++j) {
        float p = __expf(sc[kn][j] - m_j[j]);
        l_j[j] += p;
        Pl[w][(fg * 4 + j) * PADK + kn * 16 + fr] = f2bf(p);
      }
    }
    // rescale O accumulators
    #pragma unroll
    for (int dn = 0; dn < 4; ++dn)
      #pragma unroll
      for (int j = 0; j < 4; ++j) oa[dn][j] *= f_j[j];
    // PV: O(16q x 64d) += P(16q x 64k) * V(64k x 64d)
    #pragma unroll
    for (int kk = 0; kk < 2; ++kk) {
      bf16x8 ap = *(const bf16x8*)(&Pl[w][fr * PADK + kk * 32 + fg * 8]);
      #pragma unroll
      for (int dn = 0; dn < 4; ++dn) {
        bf16x8 bv = *(const bf16x8*)(Vt + (dn * 16 + fr) * PADK + kk * 32 + fg * 8);
        oa[dn] = __builtin_amdgcn_mfma_f32_16x16x32_bf16(ap, bv, oa[dn], 0, 0, 0);
      }
    }
  }

  // final l reduction across fr lanes
  #pragma unroll
  for (int j = 0; j < 4; ++j) {
    float l = l_j[j];
    l += __shfl_xor(l, 1, 64);
    l += __shfl_xor(l, 2, 64);
    l += __shfl_xor(l, 4, 64);
    l += __shfl_xor(l, 8, 64);
    l_j[j] = 1.f / l;
  }
  // O -> LDS (reuse Kb) -> coalesced global store
  __syncthreads();
  ushort* Ol = Kb;
  #pragma unroll
  for (int dn = 0; dn < 4; ++dn)
    #pragma unroll
    for (int j = 0; j < 4; ++j)
      Ol[(w * 16 + fg * 4 + j) * PADK + dn * 16 + fr] = f2bf(oa[dn][j] * l_j[j]);
  __syncthreads();
  {
    int q = t >> 2, sg = t & 3;
    int qpos = qb0 + q;
    u16x8 o0 = *(const u16x8*)(Ol + q * PADK + sg * 16);
    u16x8 o1 = *(const u16x8*)(Ol + q * PADK + sg * 16 + 8);
    ushort* op = aout + ((size_t)b * S_ + qpos) * E_ + h * 64 + sg * 16;
    *(u16x8*)op = o0;
    *(u16x8*)(op + 8) = o1;
  }
}

// ------------------------- global attention for token 0 -------------------------
// gkv is bf16 [B*S][1536] (k | v for the global projection).
__global__ __launch_bounds__(256) void attn_global_kernel(
    const float* __restrict__ qg0, const ushort* __restrict__ gkv,
    const int* __restrict__ mask, ushort* __restrict__ aout) {
  __shared__ float qs[64];
  __shared__ float probs[S_];
  __shared__ float tmp[4];
  __shared__ float pacc[256];
  int h = blockIdx.x, b = blockIdx.y;
  int t = threadIdx.x;
  if (t < 16) *(float4*)&qs[t * 4] = *(const float4*)(qg0 + b * E_ + h * 64 + t * 4);
  __syncthreads();
  float sv[8];
  float lmax = -3.0e38f;
  #pragma unroll
  for (int i = 0; i < 8; ++i) {
    int s = i * 256 + t;
    const ushort* kr = gkv + ((size_t)b * S_ + s) * 1536 + h * 64;
    float sum = 0.f;
    #pragma unroll
    for (int d = 0; d < 64; ++d) sum += qs[d] * bf2f(kr[d]);
    sv[i] = (mask[b * S_ + s] == 1) ? sum : -1e9f;
    lmax = fmaxf(lmax, sv[i]);
  }
  float gmax = blockAllMax<4>(lmax, tmp, t);
  float lsum = 0.f;
  #pragma unroll
  for (int i = 0; i < 8; ++i) {
    float e = __expf(sv[i] - gmax);
    probs[i * 256 + t] = e;
    lsum += e;
  }
  float gsum = blockAllSum<4>(lsum, tmp, t);
  float inv = 1.f / gsum;
  __syncthreads();
  int d = t & 63, grp = t >> 6;
  float accd = 0.f;
  for (int i = 0; i < 512; ++i) {
    int s = grp * 512 + i;
    accd += probs[s] * bf2f(gkv[((size_t)b * S_ + s) * 1536 + 768 + h * 64 + d]);
  }
  pacc[t] = accd;
  __syncthreads();
  if (t < 64) {
    float o = (pacc[t] + pacc[t + 64] + pacc[t + 128] + pacc[t + 192]) * inv;
    aout[((size_t)b * S_) * E_ + h * 64 + t] = f2bf(o);
  }
}

// ------------------------- qg0 = x[:,0] @ Wg[:, :E] + bg[:E], scaled ----------
__global__ void qg0_kernel(const float* __restrict__ x, const float* __restrict__ Wg,
                           const float* __restrict__ bg, float* __restrict__ qg0) {
  int n = blockIdx.x * 256 + threadIdx.x;
  int b = blockIdx.y;
  const float* xr = x + (size_t)b * S_ * E_;
  float acc = bg[n];
  for (int k = 0; k < E_; ++k) acc += xr[k] * Wg[(size_t)k * (3 * E_) + n];
  qg0[b * E_ + n] = acc * 0.125f;
}

// ------------------------- classification head -------------------------
__global__ void cls_kernel(const float* __restrict__ x, const float* __restrict__ cw,
                           const float* __restrict__ cb, float* __restrict__ cls) {
  int n = blockIdx.x * 256 + threadIdx.x;
  int b = blockIdx.y;
  const float* xr = x + (size_t)b * S_ * E_;
  float acc = cb[n];
  for (int k = 0; k < E_; ++k) acc += xr[k] * cw[(size_t)k * E_ + n];
  cls[b * E_ + n] = tanhf(acc);
}

__global__ void out_kernel(const float* __restrict__ cls, const float* __restrict__ ow,
                           const float* __restrict__ ob, float* __restrict__ out) {
  int t = threadIdx.x;
  if (t < B_ * NL_) {
    int b = t / NL_, n = t % NL_;
    float acc = ob[n];
    for (int k = 0; k < E_; ++k) acc += cls[b * E_ + k] * ow[(size_t)k * NL_ + n];
    out[t] = acc;
  }
}

// ------------------------- launch -------------------------
extern "C" void kernel_launch(void* const* d_in, const int* in_sizes, int n_in,
                              void* d_out, int out_size, void* d_ws, size_t ws_size,
                              hipStream_t stream) {
  const int* ids   = (const int*)d_in[0];
  const int* mask  = (const int*)d_in[1];
  const int* tti   = (const int*)d_in[2];
  const float* we  = (const float*)d_in[3];
  const float* pe  = (const float*)d_in[4];
  const float* te  = (const float*)d_in[5];
  const float* lng = (const float*)d_in[6];
  const float* lnb = (const float*)d_in[7];
  const float* Wqkv = (const float*)d_in[8];
  const float* bqkv = (const float*)d_in[9];
  const float* Wg   = (const float*)d_in[10];
  const float* bg   = (const float*)d_in[11];
  const float* Wo   = (const float*)d_in[12];
  const float* bo   = (const float*)d_in[13];
  const float* ln1g = (const float*)d_in[14];
  const float* ln1b = (const float*)d_in[15];
  const float* Wi   = (const float*)d_in[16];
  const float* bi   = (const float*)d_in[17];
  const float* Wf   = (const float*)d_in[18];
  const float* bf_  = (const float*)d_in[19];
  const float* ln2g = (const float*)d_in[20];
  const float* ln2b = (const float*)d_in[21];
  const float* cw   = (const float*)d_in[22];
  const float* cb   = (const float*)d_in[23];
  const float* ow   = (const float*)d_in[24];
  const float* ob   = (const float*)d_in[25];
  float* out = (float*)d_out;

  char* ws = (char*)d_ws;
  size_t off = 0;
  auto alloc = [&](size_t bytes) { void* p = ws + off; off += (bytes + 255) & ~(size_t)255; return p; };
  const size_t BSE = (size_t)B_ * S_ * E_;
  int*    pos  = (int*)alloc((size_t)B_ * S_ * 4);
  float*  x    = (float*)alloc(BSE * 4);
  float*  y    = (float*)alloc(BSE * 4);
  ushort* xb   = (ushort*)alloc(BSE * 2);
  ushort* ab   = (ushort*)alloc(BSE * 2);
  ushort* qkvb = (ushort*)alloc((size_t)B_ * S_ * 2304 * 2);   // bf16 qkv
  ushort* gkvb = (ushort*)alloc((size_t)B_ * S_ * 1536 * 2);   // bf16 global k|v
  float*  qg0  = (float*)alloc((size_t)B_ * E_ * 4);
  float*  cls  = (float*)alloc((size_t)B_ * E_ * 4);
  // per-layer transposed bf16 weights
  ushort* WqkvT = (ushort*)alloc((size_t)2304 * 768 * 2);
  ushort* WgT   = (ushort*)alloc((size_t)2304 * 768 * 2);
  ushort* WoT   = (ushort*)alloc((size_t)768 * 768 * 2);
  ushort* WiT   = (ushort*)alloc((size_t)3072 * 768 * 2);
  ushort* WfT   = (ushort*)alloc((size_t)768 * 3072 * 2);
  // FFN hidden (bf16, B*S*FF = 25.2MB) aliases the contiguous qkvb+gkvb
  // region (31.5MB) — both dead in the FFN phase.
  ushort* hb = qkvb;

  const int M = B_ * S_;

  pos_ids_kernel<<<B_, 256, 0, stream>>>(mask, pos);
  embed_ln_kernel<<<M, 256, 0, stream>>>(ids, pos, tti, we, pe, te, lng, lnb, x, xb);

  for (int l = 0; l < L_; ++l) {
    const float* Wqkv_l = Wqkv + (size_t)l * E_ * 3 * E_;
    const float* bqkv_l = bqkv + (size_t)l * 3 * E_;
    const float* Wg_l   = Wg + (size_t)l * E_ * 3 * E_;
    const float* bg_l   = bg + (size_t)l * 3 * E_;
    const float* Wo_l   = Wo + (size_t)l * E_ * E_;
    const float* bo_l   = bo + (size_t)l * E_;
    const float* Wi_l   = Wi + (size_t)l * E_ * FF_;
    const float* bi_l   = bi + (size_t)l * FF_;
    const float* Wf_l   = Wf + (size_t)l * FF_ * E_;
    const float* bf_l   = bf_ + (size_t)l * E_;

    transposeW_kernel<<<dim3(2304 / 32, 768 / 32), 256, 0, stream>>>(Wqkv_l, WqkvT, 768, 2304);
    transposeW_kernel<<<dim3(2304 / 32, 768 / 32), 256, 0, stream>>>(Wg_l, WgT, 768, 2304);
    transposeW_kernel<<<dim3(768 / 32, 768 / 32), 256, 0, stream>>>(Wo_l, WoT, 768, 768);
    transposeW_kernel<<<dim3(3072 / 32, 768 / 32), 256, 0, stream>>>(Wi_l, WiT, 768, 3072);
    transposeW_kernel<<<dim3(768 / 32, 3072 / 32), 256, 0, stream>>>(Wf_l, WfT, 3072, 768);

    // qkv = x @ Wqkv + b  (bf16 out)
    gemm_mfma<0><<<dim3(2304 / 128, M / 128), 256, 0, stream>>>(
        xb, WqkvT, bqkv_l, nullptr, nullptr, qkvb, M, 2304, 768);
    // gkv = x @ Wg[:, E:] + bg[E:]  (bf16 out)
    gemm_mfma<0><<<dim3(1536 / 128, M / 128), 256, 0, stream>>>(
        xb, WgT + (size_t)E_ * 768, bg_l + E_, nullptr, nullptr, gkvb, M, 1536, 768);
    qg0_kernel<<<dim3(E_ / 256, B_), 256, 0, stream>>>(x, Wg_l, bg_l, qg0);

    attn_local_kernel<<<dim3(S_ / 64, H_, B_), 256, 0, stream>>>(qkvb, mask, ab);
    attn_global_kernel<<<dim3(H_, B_), 256, 0, stream>>>(qg0, gkvb, mask, ab);

    // y = a @ Wo + bo + x ; x = LN(y)
    gemm_mfma<2><<<dim3(768 / 128, M / 128), 256, 0, stream>>>(
        ab, WoT, bo_l, x, y, nullptr, M, 768, 768);
    ln_kernel<<<M, 256, 0, stream>>>(y, ln1g + (size_t)l * E_, ln1b + (size_t)l * E_, x, xb);

    // h = gelu(x @ Wi + bi) (bf16) ; y = h @ Wf + bf + x ; x = LN(y)
    gemm_mfma<1><<<dim3(3072 / 128, M / 128), 256, 0, stream>>>(
        xb, WiT, bi_l, nullptr, nullptr, hb, M, 3072, 768);
    gemm_mfma<2><<<dim3(768 / 128, M / 128), 256, 0, stream>>>(
        hb, WfT, bf_l, x, y, nullptr, M, 768, 3072);
    ln_kernel<<<M, 256, 0, stream>>>(y, ln2g + (size_t)l * E_, ln2b + (size_t)l * E_, x, xb);
  }

  cls_kernel<<<dim3(E_ / 256, B_), 256, 0, stream>>>(x, cw, cb, cls);
  out_kernel<<<1, 64, 0, stream>>>(cls, ow, ob, out);
}

// Round 6
// 1048.371 us; speedup vs baseline: 3.4801x; 1.0899x over previous
//
#include <hip/hip_runtime.h>
#include <hip/hip_bf16.h>
#include <math.h>

#define B_  2
#define S_  2048
#define L_  2
#define E_  768
#define H_  12
#define D_  64
#define W_  256
#define FF_ 3072
#define NL_ 9

typedef __attribute__((ext_vector_type(8))) short bf16x8;
typedef __attribute__((ext_vector_type(8))) unsigned short u16x8;
typedef __attribute__((ext_vector_type(4))) float f32x4;

__device__ __forceinline__ ushort f2bf(float f) {
  __hip_bfloat16 h = __float2bfloat16(f);
  return *(ushort*)&h;
}
__device__ __forceinline__ float bf2f(ushort u) {
  union { unsigned int i; float f; } c;
  c.i = ((unsigned int)u) << 16;
  return c.f;
}

__device__ __forceinline__ void gload_lds16(const void* g, void* l) {
  __builtin_amdgcn_global_load_lds(
      (const __attribute__((address_space(1))) void*)g,
      (__attribute__((address_space(3))) void*)l, 16, 0, 0);
}

// ------------------------- reduction helpers -------------------------
__device__ __forceinline__ float waveAllSum(float v) {
  #pragma unroll
  for (int off = 1; off < 64; off <<= 1) v += __shfl_xor(v, off, 64);
  return v;
}
__device__ __forceinline__ float waveAllMax(float v) {
  #pragma unroll
  for (int off = 1; off < 64; off <<= 1) v = fmaxf(v, __shfl_xor(v, off, 64));
  return v;
}
template<int NW>
__device__ __forceinline__ float blockAllSum(float v, float* tmp, int t) {
  v = waveAllSum(v);
  __syncthreads();
  if ((t & 63) == 0) tmp[t >> 6] = v;
  __syncthreads();
  float r = 0.f;
  #pragma unroll
  for (int i = 0; i < NW; ++i) r += tmp[i];
  return r;
}
template<int NW>
__device__ __forceinline__ float blockAllMax(float v, float* tmp, int t) {
  v = waveAllMax(v);
  __syncthreads();
  if ((t & 63) == 0) tmp[t >> 6] = v;
  __syncthreads();
  float r = tmp[0];
  #pragma unroll
  for (int i = 1; i < NW; ++i) r = fmaxf(r, tmp[i]);
  return r;
}

// ------------------------- pos ids (cumsum) -------------------------
__global__ void pos_ids_kernel(const int* __restrict__ mask, int* __restrict__ pos) {
  __shared__ int part[256];
  int b = blockIdx.x, t = threadIdx.x;
  const int* mr = mask + b * S_;
  int* pr = pos + b * S_;
  int v[8]; int s = 0;
  #pragma unroll
  for (int j = 0; j < 8; ++j) { v[j] = mr[t * 8 + j]; s += v[j]; }
  part[t] = s;
  __syncthreads();
  for (int off = 1; off < 256; off <<= 1) {
    int add = (t >= off) ? part[t - off] : 0;
    __syncthreads();
    part[t] += add;
    __syncthreads();
  }
  int run = (t == 0) ? 0 : part[t - 1];
  #pragma unroll
  for (int j = 0; j < 8; ++j) { run += v[j]; pr[t * 8 + j] = run * v[j] + 1; }
}

// ------------------------- embedding + LayerNorm (fp32 x + bf16 xb) ------------
__global__ __launch_bounds__(256) void embed_ln_kernel(
    const int* __restrict__ ids, const int* __restrict__ pos, const int* __restrict__ tti,
    const float* __restrict__ we, const float* __restrict__ pe, const float* __restrict__ te,
    const float* __restrict__ g, const float* __restrict__ bb,
    float* __restrict__ x, ushort* __restrict__ xb) {
  __shared__ float tmp[4];
  int row = blockIdx.x, t = threadIdx.x;
  int id = ids[row], pid = pos[row], tt = tti[row];
  float v[3]; float s = 0.f;
  #pragma unroll
  for (int j = 0; j < 3; ++j) {
    int col = t + j * 256;
    v[j] = we[(size_t)id * E_ + col] + pe[(size_t)pid * E_ + col] + te[(size_t)tt * E_ + col];
    s += v[j];
  }
  float mean = blockAllSum<4>(s, tmp, t) * (1.f / E_);
  float ss = 0.f;
  #pragma unroll
  for (int j = 0; j < 3; ++j) { float d = v[j] - mean; ss += d * d; }
  float var = blockAllSum<4>(ss, tmp, t) * (1.f / E_);
  float rstd = rsqrtf(var + 1e-5f);
  float* op = x + (size_t)row * E_;
  ushort* ob = xb + (size_t)row * E_;
  #pragma unroll
  for (int j = 0; j < 3; ++j) {
    int col = t + j * 256;
    float o = (v[j] - mean) * rstd * g[col] + bb[col];
    op[col] = o;
    ob[col] = f2bf(o);
  }
}

// ---------------- fused partial-sum + bias + residual + LayerNorm ----------------
// v = bias + res + sum_p yp[p]; then LN -> out fp32 + outb bf16. out may alias res.
template<int NP>
__global__ __launch_bounds__(256) void ln_red_kernel(
    const float* yp, const float* bias, const float* res,
    const float* g, const float* bb, float* out, ushort* outb) {
  __shared__ float tmp[4];
  int row = blockIdx.x, t = threadIdx.x;
  const size_t MN = (size_t)B_ * S_ * E_;
  float v[3]; float s = 0.f;
  #pragma unroll
  for (int j = 0; j < 3; ++j) {
    int col = t + j * 256;
    float a = bias[col] + res[(size_t)row * E_ + col];
    #pragma unroll
    for (int p = 0; p < NP; ++p) a += yp[p * MN + (size_t)row * E_ + col];
    v[j] = a; s += a;
  }
  float mean = blockAllSum<4>(s, tmp, t) * (1.f / E_);
  float ss = 0.f;
  #pragma unroll
  for (int j = 0; j < 3; ++j) { float d = v[j] - mean; ss += d * d; }
  float var = blockAllSum<4>(ss, tmp, t) * (1.f / E_);
  float rstd = rsqrtf(var + 1e-5f);
  float* op = out + (size_t)row * E_;
  ushort* ob = outb + (size_t)row * E_;
  #pragma unroll
  for (int j = 0; j < 3; ++j) {
    int col = t + j * 256;
    float o = (v[j] - mean) * rstd * g[col] + bb[col];
    op[col] = o;
    ob[col] = f2bf(o);
  }
}

// ------------------------- weight transpose + bf16 convert -------------------------
// src fp32 [K][N] row-major -> dst bf16 [N][K]
__global__ __launch_bounds__(256) void transposeW_kernel(
    const float* __restrict__ src, ushort* __restrict__ dst, int K, int N) {
  __shared__ float tile[32][33];
  int k0 = blockIdx.y * 32, n0 = blockIdx.x * 32;
  int t = threadIdx.x;
  #pragma unroll
  for (int i = 0; i < 4; ++i) {
    int idx = t + i * 256; int r = idx >> 5, cc = idx & 31;
    tile[r][cc] = src[(size_t)(k0 + r) * N + n0 + cc];
  }
  __syncthreads();
  #pragma unroll
  for (int i = 0; i < 4; ++i) {
    int idx = t + i * 256; int r = idx >> 5, cc = idx & 31;
    dst[(size_t)(n0 + r) * K + k0 + cc] = f2bf(tile[cc][r]);
  }
}

// ------------------------- V transpose: qkvb -> vT[b][h][d][s] -----------------
__global__ __launch_bounds__(256) void transposeV_kernel(
    const ushort* __restrict__ qkvb, ushort* __restrict__ vT) {
  __shared__ ushort tile[64][72];
  int s0 = blockIdx.x * 64;
  int h = blockIdx.y, b = blockIdx.z;
  int t = threadIdx.x;
  {
    int r = t >> 2, cg = (t & 3) * 16;
    const ushort* src = qkvb + (size_t)(b * S_ + s0 + r) * 2304 + 1536 + h * 64 + cg;
    *(u16x8*)&tile[r][cg] = *(const u16x8*)src;
    *(u16x8*)&tile[r][cg + 8] = *(const u16x8*)(src + 8);
  }
  __syncthreads();
  {
    int d = t >> 2, sg = (t & 3) * 16;
    ushort o[16];
    #pragma unroll
    for (int j = 0; j < 16; ++j) o[j] = tile[sg + j][d];
    ushort* dst = vT + ((size_t)(b * H_ + h) * 64 + d) * S_ + s0 + sg;
    *(u16x8*)dst = *(u16x8*)&o[0];
    *(u16x8*)(dst + 8) = *(u16x8*)&o[8];
  }
}

// ------------------------- bf16 MFMA GEMM -------------------------
// C[m,n] = A[m,:] . BT[n,:]   (A: [M][K] bf16, BT: [N][K] bf16)
// K-chunked via blockIdx.z (gridDim.z chunks).
// EPI 0: bias -> bf16; EPI 1: bias+gelu -> bf16; EPI 3: fp32 partial (no bias)
template<int EPI>
__global__ __launch_bounds__(256) void gemm_mfma(
    const ushort* __restrict__ A, const ushort* __restrict__ BT,
    const float* __restrict__ bias, const float* __restrict__ res,
    float* __restrict__ Cf, ushort* __restrict__ Cb, int M, int N, int K) {
  __shared__ __align__(16) ushort As[128 * 32];
  __shared__ __align__(16) ushort Bs[128 * 32];
  int t = threadIdx.x;
  int w = t >> 6, lane = t & 63;
  int wr = w >> 1, wc = w & 1;
  int fr = lane & 15, fg = lane >> 4;
  int m0 = blockIdx.y * 128, n0 = blockIdx.x * 128;
  int Kc = K / (int)gridDim.z;
  int kbeg = (int)blockIdx.z * Kc;
  f32x4 acc[4][4];
  #pragma unroll
  for (int m = 0; m < 4; ++m)
    #pragma unroll
    for (int n = 0; n < 4; ++n) acc[m][n] = (f32x4)0.f;

  int lrow = lane >> 2, lcol = (lane & 3) * 8;
  for (int k0 = kbeg; k0 < kbeg + Kc; k0 += 32) {
    #pragma unroll
    for (int j = 0; j < 2; ++j) {
      int rbase = w * 32 + j * 16;
      gload_lds16(A + (size_t)(m0 + rbase + lrow) * K + k0 + lcol,
                  (void*)(As + rbase * 32));
      gload_lds16(BT + (size_t)(n0 + rbase + lrow) * K + k0 + lcol,
                  (void*)(Bs + rbase * 32));
    }
    __syncthreads();
    bf16x8 af[4], bf[4];
    #pragma unroll
    for (int m = 0; m < 4; ++m)
      af[m] = *(const bf16x8*)(As + (wr * 64 + m * 16 + fr) * 32 + fg * 8);
    #pragma unroll
    for (int n = 0; n < 4; ++n)
      bf[n] = *(const bf16x8*)(Bs + (wc * 64 + n * 16 + fr) * 32 + fg * 8);
    #pragma unroll
    for (int m = 0; m < 4; ++m)
      #pragma unroll
      for (int n = 0; n < 4; ++n)
        acc[m][n] = __builtin_amdgcn_mfma_f32_16x16x32_bf16(af[m], bf[n], acc[m][n], 0, 0, 0);
    __syncthreads();
  }

  #pragma unroll
  for (int n = 0; n < 4; ++n) {
    int col = n0 + wc * 64 + n * 16 + fr;
    float bv = (EPI == 3) ? 0.f : bias[col];
    #pragma unroll
    for (int m = 0; m < 4; ++m) {
      int rbase = m0 + wr * 64 + m * 16 + fg * 4;
      #pragma unroll
      for (int r = 0; r < 4; ++r) {
        int row = rbase + r;
        float v = acc[m][n][r] + bv;
        if (EPI == 0) {
          Cb[(size_t)row * N + col] = f2bf(v);
        } else if (EPI == 1) {
          v = 0.5f * v * (1.f + erff(v * 0.70710678118654752f));
          Cb[(size_t)row * N + col] = f2bf(v);
        } else {
          Cf[(size_t)blockIdx.z * M * N + (size_t)row * N + col] = v;
        }
      }
    }
  }
}

// ------------------------- local sliding-window attention (MFMA, barrier-free) --
// One block = 4 waves = 64 queries of one (b,h); wave owns 16 queries.
// K consumed as direct-global B-frags (qkv rows); V as direct-global A-frags
// from the vT buffer (computing O^T). P per-wave in LDS. OOB tiles skipped.
#define PADK 72
__global__ __launch_bounds__(256) void attn_local_kernel(
    const ushort* __restrict__ qkv, const ushort* __restrict__ vT,
    const int* __restrict__ mask, ushort* __restrict__ aout) {
  __shared__ __align__(16) ushort Pl[4][16 * PADK];
  __shared__ float k0s[64], v0s[64];
  int t = threadIdx.x;
  int w = t >> 6, lane = t & 63;
  int fr = lane & 15, fg = lane >> 4;
  int qb0 = blockIdx.x * 64;
  int h = blockIdx.y, b = blockIdx.z;
  int kbase = ((qb0 >> 8) << 8) - 256;
  const ushort* base = qkv + (size_t)b * S_ * 2304;
  const ushort* vbase = vT + (size_t)(b * H_ + h) * 64 * S_;
  const int* mrow = mask + b * S_;

  if (t < 64) k0s[t] = bf2f(base[E_ + h * 64 + t]);
  else if (t < 128) v0s[t - 64] = bf2f(base[2 * E_ + h * 64 + (t - 64)]);
  int gmask = mrow[0];

  // Q A-fragments, pre-scaled by 1/8 (exact pow2 scale)
  int qrowA = qb0 + w * 16 + fr;
  bf16x8 afq[2];
  #pragma unroll
  for (int kk = 0; kk < 2; ++kk) {
    u16x8 qv = *(const u16x8*)(base + (size_t)qrowA * 2304 + h * 64 + kk * 32 + fg * 8);
    ushort o[8];
    #pragma unroll
    for (int j = 0; j < 8; ++j) o[j] = f2bf(bf2f(qv[j]) * 0.125f);
    afq[kk] = *(bf16x8*)o;
  }
  __syncthreads();

  // global key-0 score per A-row query, redistribute to C-row order
  float s0 = 0.f;
  #pragma unroll
  for (int kk = 0; kk < 2; ++kk) {
    ushort* ap = (ushort*)&afq[kk];
    #pragma unroll
    for (int j = 0; j < 8; ++j) s0 += bf2f(ap[j]) * k0s[kk * 32 + fg * 8 + j];
  }
  s0 += __shfl_xor(s0, 16, 64);
  s0 += __shfl_xor(s0, 32, 64);

  float m_j[4], l_j[4];
  f32x4 oa[4];      // O^T: lane holds q=fr; oa[dn][r] at d = dn*16 + fg*4 + r
  #pragma unroll
  for (int j = 0; j < 4; ++j) {
    float s0q = __shfl(s0, fg * 4 + j, 64);
    m_j[j] = gmask ? s0q : -3.0e38f;
    l_j[j] = (gmask && fr == 0) ? 1.f : 0.f;
  }
  #pragma unroll
  for (int dn = 0; dn < 4; ++dn) {
    f32x4 t4;
    #pragma unroll
    for (int r = 0; r < 4; ++r) t4[r] = gmask ? v0s[dn * 16 + fg * 4 + r] : 0.f;
    oa[dn] = t4;
  }
  int srcl = (fr >> 2) << 4;
  int sel = fr & 3;

  #pragma unroll 1
  for (int tile = 0; tile < 12; ++tile) {
    int r0 = kbase + tile * 64;
    if (r0 < 0 || r0 >= S_) continue;    // block-uniform skip of OOB tiles
    // scores S(16q x 64k): B-frags directly from K global rows
    f32x4 sc[4];
    #pragma unroll
    for (int kn = 0; kn < 4; ++kn) {
      const ushort* kp = base + (size_t)(r0 + kn * 16 + fr) * 2304 + E_ + h * 64 + fg * 8;
      bf16x8 bk0 = *(const bf16x8*)kp;
      bf16x8 bk1 = *(const bf16x8*)(kp + 32);
      f32x4 s = (f32x4)0.f;
      s = __builtin_amdgcn_mfma_f32_16x16x32_bf16(afq[0], bk0, s, 0, 0, 0);
      s = __builtin_amdgcn_mfma_f32_16x16x32_bf16(afq[1], bk1, s, 0, 0, 0);
      sc[kn] = s;
    }
    // masking: C elem (q = qb0 + w*16 + fg*4 + j, k = r0 + kn*16 + fr)
    int qrowC = qb0 + w * 16 + fg * 4;
    #pragma unroll
    for (int kn = 0; kn < 4; ++kn) {
      int kpos = r0 + kn * 16 + fr;
      float pn = (kpos != 0 && mrow[kpos] == 1) ? 0.f : -1e9f;
      #pragma unroll
      for (int j = 0; j < 4; ++j) {
        int dd = kpos - (qrowC + j);
        bool okr = (dd <= W_) && (dd >= -W_);
        sc[kn][j] = okr ? (sc[kn][j] + pn) : -1e9f;
      }
    }
    // online softmax update (q-row = fg*4+j, reduce across fr lanes)
    float f_j[4];
    #pragma unroll
    for (int j = 0; j < 4; ++j) {
      float tm = fmaxf(fmaxf(sc[0][j], sc[1][j]), fmaxf(sc[2][j], sc[3][j]));
      tm = fmaxf(tm, __shfl_xor(tm, 1, 64));
      tm = fmaxf(tm, __shfl_xor(tm, 2, 64));
      tm = fmaxf(tm, __shfl_xor(tm, 4, 64));
      tm = fmaxf(tm, __shfl_xor(tm, 8, 64));
      float mn = fmaxf(m_j[j], tm);
      float f = __expf(m_j[j] - mn);
      m_j[j] = mn;
      f_j[j] = f;
      l_j[j] *= f;
    }
    // P = exp(s - m): per-lane l partials, write P rows [q][k] to per-wave LDS
    #pragma unroll
    for (int kn = 0; kn < 4; ++kn) {
      #pragma unroll
      for (int j = 0; j < 4; ++j) {
        float p = __expf(sc[kn][j] - m_j[j]);
        l_j[j] += p;
        Pl[w][(fg * 4 + j) * PADK + kn * 16 + fr] = f2bf(p);
      }
    }
    // redistribute f to q=fr lanes, rescale O^T
    float g0 = __shfl(f_j[0], srcl, 64), g1 = __shfl(f_j[1], srcl, 64);
    float g2 = __shfl(f_j[2], srcl, 64), g3 = __shfl(f_j[3], srcl, 64);
    float fq = sel == 0 ? g0 : sel == 1 ? g1 : sel == 2 ? g2 : g3;
    #pragma unroll
    for (int dn = 0; dn < 4; ++dn)
      #pragma unroll
      for (int r = 0; r < 4; ++r) oa[dn][r] *= fq;
    // PV: O^T(64d x 16q) += V^T(d,k) * P^T(k,q); A-frags direct from vT global
    bf16x8 av[2][4];
    #pragma unroll
    for (int kk = 0; kk < 2; ++kk)
      #pragma unroll
      for (int dn = 0; dn < 4; ++dn)
        av[kk][dn] = *(const bf16x8*)(vbase + (size_t)(dn * 16 + fr) * S_ + r0 + kk * 32 + fg * 8);
    #pragma unroll
    for (int kk = 0; kk < 2; ++kk) {
      bf16x8 ap = *(const bf16x8*)(&Pl[w][fr * PADK + kk * 32 + fg * 8]);
      #pragma unroll
      for (int dn = 0; dn < 4; ++dn)
        oa[dn] = __builtin_amdgcn_mfma_f32_16x16x32_bf16(av[kk][dn], ap, oa[dn], 0, 0, 0);
    }
  }

  // final l reduction across fr lanes, redistribute 1/l to q=fr lanes
  #pragma unroll
  for (int j = 0; j < 4; ++j) {
    float l = l_j[j];
    l += __shfl_xor(l, 1, 64);
    l += __shfl_xor(l, 2, 64);
    l += __shfl_xor(l, 4, 64);
    l += __shfl_xor(l, 8, 64);
    l_j[j] = 1.f / l;
  }
  float i0 = __shfl(l_j[0], srcl, 64), i1 = __shfl(l_j[1], srcl, 64);
  float i2 = __shfl(l_j[2], srcl, 64), i3 = __shfl(l_j[3], srcl, 64);
  float invq = sel == 0 ? i0 : sel == 1 ? i1 : sel == 2 ? i2 : i3;

  // O^T -> LDS (alias Pl) -> coalesced global store
  __syncthreads();
  ushort* Ol = &Pl[0][0];
  #pragma unroll
  for (int dn = 0; dn < 4; ++dn)
    #pragma unroll
    for (int r = 0; r < 4; ++r)
      Ol[(w * 16 + fr) * PADK + dn * 16 + fg * 4 + r] = f2bf(oa[dn][r] * invq);
  __syncthreads();
  {
    int q = t >> 2, sg = t & 3;
    int qpos = qb0 + q;
    u16x8 o0 = *(const u16x8*)(Ol + q * PADK + sg * 16);
    u16x8 o1 = *(const u16x8*)(Ol + q * PADK + sg * 16 + 8);
    ushort* op = aout + ((size_t)b * S_ + qpos) * E_ + h * 64 + sg * 16;
    *(u16x8*)op = o0;
    *(u16x8*)(op + 8) = o1;
  }
}

// ------------------- global attention for token 0 (split-s flash) ---------------
#define GSPLIT 8
__global__ __launch_bounds__(256) void attn_global_part(
    const float* __restrict__ qg0, const ushort* __restrict__ gkv,
    const int* __restrict__ mask, float* __restrict__ gws) {
  __shared__ float qs[64];
  __shared__ float ps[256];
  __shared__ float tmp[4];
  __shared__ float pacc[256];
  int h = blockIdx.x, b = blockIdx.y, c = blockIdx.z;
  int t = threadIdx.x;
  if (t < 16) *(float4*)&qs[t * 4] = *(const float4*)(qg0 + b * E_ + h * 64 + t * 4);
  __syncthreads();
  int s = c * 256 + t;
  const ushort* kr = gkv + ((size_t)b * S_ + s) * 1536 + h * 64;
  float sum = 0.f;
  #pragma unroll
  for (int d8 = 0; d8 < 8; ++d8) {
    u16x8 kv = *(const u16x8*)(kr + d8 * 8);
    #pragma unroll
    for (int j = 0; j < 8; ++j) sum += qs[d8 * 8 + j] * bf2f(kv[j]);
  }
  float sv = (mask[b * S_ + s] == 1) ? sum : -1e9f;
  float mc = blockAllMax<4>(sv, tmp, t);
  float p = __expf(sv - mc);
  ps[t] = p;
  float lc = blockAllSum<4>(p, tmp, t);
  __syncthreads();
  int d = t & 63, grp = t >> 6;
  float acc = 0.f;
  for (int i = 0; i < 64; ++i) {
    int sl = grp * 64 + i;
    acc += ps[sl] * bf2f(gkv[((size_t)b * S_ + c * 256 + sl) * 1536 + 768 + h * 64 + d]);
  }
  pacc[t] = acc;
  __syncthreads();
  float* gw = gws + ((size_t)(b * H_ + h) * GSPLIT + c) * 66;
  if (t < 64) gw[2 + t] = pacc[t] + pacc[t + 64] + pacc[t + 128] + pacc[t + 192];
  if (t == 0) { gw[0] = mc; gw[1] = lc; }
}

__global__ void attn_global_comb(const float* __restrict__ gws, ushort* __restrict__ aout) {
  int h = blockIdx.x, b = blockIdx.y, t = threadIdx.x;   // 64 threads
  const float* gw = gws + (size_t)(b * H_ + h) * GSPLIT * 66;
  float M = -3.0e38f;
  #pragma unroll
  for (int c = 0; c < GSPLIT; ++c) M = fmaxf(M, gw[c * 66]);
  float l = 0.f, o = 0.f;
  #pragma unroll
  for (int c = 0; c < GSPLIT; ++c) {
    float wgt = __expf(gw[c * 66] - M);
    l += wgt * gw[c * 66 + 1];
    o += wgt * gw[c * 66 + 2 + t];
  }
  aout[((size_t)b * S_) * E_ + h * 64 + t] = f2bf(o / l);
}

// ------------------------- qg0 = x[:,0] @ Wg[:, :E] + bg[:E], scaled ----------
__global__ void qg0_kernel(const float* __restrict__ x, const float* __restrict__ Wg,
                           const float* __restrict__ bg, float* __restrict__ qg0) {
  int n = blockIdx.x * 256 + threadIdx.x;
  int b = blockIdx.y;
  const float* xr = x + (size_t)b * S_ * E_;
  float acc = bg[n];
  for (int k = 0; k < E_; ++k) acc += xr[k] * Wg[(size_t)k * (3 * E_) + n];
  qg0[b * E_ + n] = acc * 0.125f;
}

// ------------------------- classification head -------------------------
__global__ void cls_kernel(const float* __restrict__ x, const float* __restrict__ cw,
                           const float* __restrict__ cb, float* __restrict__ cls) {
  int n = blockIdx.x * 256 + threadIdx.x;
  int b = blockIdx.y;
  const float* xr = x + (size_t)b * S_ * E_;
  float acc = cb[n];
  for (int k = 0; k < E_; ++k) acc += xr[k] * cw[(size_t)k * E_ + n];
  cls[b * E_ + n] = tanhf(acc);
}

__global__ void out_kernel(const float* __restrict__ cls, const float* __restrict__ ow,
                           const float* __restrict__ ob, float* __restrict__ out) {
  int t = threadIdx.x;
  if (t < B_ * NL_) {
    int b = t / NL_, n = t % NL_;
    float acc = ob[n];
    for (int k = 0; k < E_; ++k) acc += cls[b * E_ + k] * ow[(size_t)k * NL_ + n];
    out[t] = acc;
  }
}

// ------------------------- launch -------------------------
extern "C" void kernel_launch(void* const* d_in, const int* in_sizes, int n_in,
                              void* d_out, int out_size, void* d_ws, size_t ws_size,
                              hipStream_t stream) {
  const int* ids   = (const int*)d_in[0];
  const int* mask  = (const int*)d_in[1];
  const int* tti   = (const int*)d_in[2];
  const float* we  = (const float*)d_in[3];
  const float* pe  = (const float*)d_in[4];
  const float* te  = (const float*)d_in[5];
  const float* lng = (const float*)d_in[6];
  const float* lnb = (const float*)d_in[7];
  const float* Wqkv = (const float*)d_in[8];
  const float* bqkv = (const float*)d_in[9];
  const float* Wg   = (const float*)d_in[10];
  const float* bg   = (const float*)d_in[11];
  const float* Wo   = (const float*)d_in[12];
  const float* bo   = (const float*)d_in[13];
  const float* ln1g = (const float*)d_in[14];
  const float* ln1b = (const float*)d_in[15];
  const float* Wi   = (const float*)d_in[16];
  const float* bi   = (const float*)d_in[17];
  const float* Wf   = (const float*)d_in[18];
  const float* bf_  = (const float*)d_in[19];
  const float* ln2g = (const float*)d_in[20];
  const float* ln2b = (const float*)d_in[21];
  const float* cw   = (const float*)d_in[22];
  const float* cb   = (const float*)d_in[23];
  const float* ow   = (const float*)d_in[24];
  const float* ob   = (const float*)d_in[25];
  float* out = (float*)d_out;

  char* ws = (char*)d_ws;
  size_t off = 0;
  auto alloc = [&](size_t bytes) { void* p = ws + off; off += (bytes + 255) & ~(size_t)255; return p; };
  const size_t BSE = (size_t)B_ * S_ * E_;
  int*    pos  = (int*)alloc((size_t)B_ * S_ * 4);
  float*  x    = (float*)alloc(BSE * 4);
  ushort* xb   = (ushort*)alloc(BSE * 2);
  ushort* ab   = (ushort*)alloc(BSE * 2);
  ushort* qkvb = (ushort*)alloc((size_t)B_ * S_ * 2304 * 2);   // bf16 qkv
  ushort* gkvb = (ushort*)alloc((size_t)B_ * S_ * 1536 * 2);   // bf16 global k|v
  ushort* vTb  = (ushort*)alloc((size_t)B_ * H_ * 64 * S_ * 2);// bf16 V^T per (b,h)
  float*  yp   = (float*)alloc(4 * BSE * 4);                   // split-K partials
  float*  qg0  = (float*)alloc((size_t)B_ * E_ * 4);
  float*  gws  = (float*)alloc((size_t)B_ * H_ * GSPLIT * 66 * 4);
  float*  cls  = (float*)alloc((size_t)B_ * E_ * 4);
  ushort* WqkvT = (ushort*)alloc((size_t)2304 * 768 * 2);
  ushort* WgT   = (ushort*)alloc((size_t)2304 * 768 * 2);
  ushort* WoT   = (ushort*)alloc((size_t)768 * 768 * 2);
  ushort* WiT   = (ushort*)alloc((size_t)3072 * 768 * 2);
  ushort* WfT   = (ushort*)alloc((size_t)768 * 3072 * 2);
  ushort* hb = qkvb;   // FFN hidden (bf16) aliases qkvb+gkvb region (dead in FFN phase)

  const int M = B_ * S_;

  pos_ids_kernel<<<B_, 256, 0, stream>>>(mask, pos);
  embed_ln_kernel<<<M, 256, 0, stream>>>(ids, pos, tti, we, pe, te, lng, lnb, x, xb);

  for (int l = 0; l < L_; ++l) {
    const float* Wqkv_l = Wqkv + (size_t)l * E_ * 3 * E_;
    const float* bqkv_l = bqkv + (size_t)l * 3 * E_;
    const float* Wg_l   = Wg + (size_t)l * E_ * 3 * E_;
    const float* bg_l   = bg + (size_t)l * 3 * E_;
    const float* Wo_l   = Wo + (size_t)l * E_ * E_;
    const float* bo_l   = bo + (size_t)l * E_;
    const float* Wi_l   = Wi + (size_t)l * E_ * FF_;
    const float* bi_l   = bi + (size_t)l * FF_;
    const float* Wf_l   = Wf + (size_t)l * FF_ * E_;
    const float* bf_l   = bf_ + (size_t)l * E_;

    transposeW_kernel<<<dim3(2304 / 32, 768 / 32), 256, 0, stream>>>(Wqkv_l, WqkvT, 768, 2304);
    transposeW_kernel<<<dim3(2304 / 32, 768 / 32), 256, 0, stream>>>(Wg_l, WgT, 768, 2304);
    transposeW_kernel<<<dim3(768 / 32, 768 / 32), 256, 0, stream>>>(Wo_l, WoT, 768, 768);
    transposeW_kernel<<<dim3(3072 / 32, 768 / 32), 256, 0, stream>>>(Wi_l, WiT, 768, 3072);
    transposeW_kernel<<<dim3(768 / 32, 3072 / 32), 256, 0, stream>>>(Wf_l, WfT, 3072, 768);

    // qkv = x @ Wqkv + b  (bf16 out)
    gemm_mfma<0><<<dim3(2304 / 128, M / 128), 256, 0, stream>>>(
        xb, WqkvT, bqkv_l, nullptr, nullptr, qkvb, M, 2304, 768);
    transposeV_kernel<<<dim3(S_ / 64, H_, B_), 256, 0, stream>>>(qkvb, vTb);
    // gkv = x @ Wg[:, E:] + bg[E:]  (bf16 out)
    gemm_mfma<0><<<dim3(1536 / 128, M / 128), 256, 0, stream>>>(
        xb, WgT + (size_t)E_ * 768, bg_l + E_, nullptr, nullptr, gkvb, M, 1536, 768);
    qg0_kernel<<<dim3(E_ / 256, B_), 256, 0, stream>>>(x, Wg_l, bg_l, qg0);

    attn_local_kernel<<<dim3(S_ / 64, H_, B_), 256, 0, stream>>>(qkvb, vTb, mask, ab);
    attn_global_part<<<dim3(H_, B_, GSPLIT), 256, 0, stream>>>(qg0, gkvb, mask, gws);
    attn_global_comb<<<dim3(H_, B_), 64, 0, stream>>>(gws, ab);

    // Wo: split-K=2 partials, then fused reduce+bias+residual+LN
    gemm_mfma<3><<<dim3(768 / 128, M / 128, 2), 256, 0, stream>>>(
        ab, WoT, nullptr, nullptr, yp, nullptr, M, 768, 768);
    ln_red_kernel<2><<<M, 256, 0, stream>>>(
        yp, bo_l, x, ln1g + (size_t)l * E_, ln1b + (size_t)l * E_, x, xb);

    // h = gelu(x @ Wi + bi) (bf16)
    gemm_mfma<1><<<dim3(3072 / 128, M / 128), 256, 0, stream>>>(
        xb, WiT, bi_l, nullptr, nullptr, hb, M, 3072, 768);
    // Wf: split-K=4 partials, then fused reduce+bias+residual+LN
    gemm_mfma<3><<<dim3(768 / 128, M / 128, 4), 256, 0, stream>>>(
        hb, WfT, nullptr, nullptr, yp, nullptr, M, 768, 3072);
    ln_red_kernel<4><<<M, 256, 0, stream>>>(
        yp, bf_l, x, ln2g + (size_t)l * E_, ln2b + (size_t)l * E_, x, xb);
  }

  cls_kernel<<<dim3(E_ / 256, B_), 256, 0, stream>>>(x, cw, cb, cls);
  out_kernel<<<1, 64, 0, stream>>>(cls, ow, ob, out);
}

// Round 8
// 824.488 us; speedup vs baseline: 4.4251x; 1.2715x over previous
//
#include <hip/hip_runtime.h>
#include <hip/hip_bf16.h>
#include <math.h>

#define B_  2
#define S_  2048
#define L_  2
#define E_  768
#define H_  12
#define D_  64
#define W_  256
#define FF_ 3072
#define NL_ 9
#define QVS 3840   // fused qkv|gkv row stride (q:0 k:768 v:1536 gk:2304 gv:3072)

typedef __attribute__((ext_vector_type(8))) short bf16x8;
typedef __attribute__((ext_vector_type(8))) unsigned short u16x8;
typedef __attribute__((ext_vector_type(4))) float f32x4;

__device__ __forceinline__ ushort f2bf(float f) {
  __hip_bfloat16 h = __float2bfloat16(f);
  return *(ushort*)&h;
}
__device__ __forceinline__ float bf2f(ushort u) {
  union { unsigned int i; float f; } c;
  c.i = ((unsigned int)u) << 16;
  return c.f;
}

__device__ __forceinline__ void gload_lds16(const void* g, void* l) {
  __builtin_amdgcn_global_load_lds(
      (const __attribute__((address_space(1))) void*)g,
      (__attribute__((address_space(3))) void*)l, 16, 0, 0);
}

// ------------------------- reduction helpers -------------------------
__device__ __forceinline__ float waveAllSum(float v) {
  #pragma unroll
  for (int off = 1; off < 64; off <<= 1) v += __shfl_xor(v, off, 64);
  return v;
}
__device__ __forceinline__ float waveAllMax(float v) {
  #pragma unroll
  for (int off = 1; off < 64; off <<= 1) v = fmaxf(v, __shfl_xor(v, off, 64));
  return v;
}
template<int NW>
__device__ __forceinline__ float blockAllSum(float v, float* tmp, int t) {
  v = waveAllSum(v);
  __syncthreads();
  if ((t & 63) == 0) tmp[t >> 6] = v;
  __syncthreads();
  float r = 0.f;
  #pragma unroll
  for (int i = 0; i < NW; ++i) r += tmp[i];
  return r;
}
template<int NW>
__device__ __forceinline__ float blockAllMax(float v, float* tmp, int t) {
  v = waveAllMax(v);
  __syncthreads();
  if ((t & 63) == 0) tmp[t >> 6] = v;
  __syncthreads();
  float r = tmp[0];
  #pragma unroll
  for (int i = 1; i < NW; ++i) r = fmaxf(r, tmp[i]);
  return r;
}

// ------------------------- pos ids (cumsum) -------------------------
__global__ void pos_ids_kernel(const int* __restrict__ mask, int* __restrict__ pos) {
  __shared__ int part[256];
  int b = blockIdx.x, t = threadIdx.x;
  const int* mr = mask + b * S_;
  int* pr = pos + b * S_;
  int v[8]; int s = 0;
  #pragma unroll
  for (int j = 0; j < 8; ++j) { v[j] = mr[t * 8 + j]; s += v[j]; }
  part[t] = s;
  __syncthreads();
  for (int off = 1; off < 256; off <<= 1) {
    int add = (t >= off) ? part[t - off] : 0;
    __syncthreads();
    part[t] += add;
    __syncthreads();
  }
  int run = (t == 0) ? 0 : part[t - 1];
  #pragma unroll
  for (int j = 0; j < 8; ++j) { run += v[j]; pr[t * 8 + j] = run * v[j] + 1; }
}

// ------------------------- embedding + LayerNorm (fp32 x + bf16 xb) ------------
__global__ __launch_bounds__(256) void embed_ln_kernel(
    const int* __restrict__ ids, const int* __restrict__ pos, const int* __restrict__ tti,
    const float* __restrict__ we, const float* __restrict__ pe, const float* __restrict__ te,
    const float* __restrict__ g, const float* __restrict__ bb,
    float* __restrict__ x, ushort* __restrict__ xb) {
  __shared__ float tmp[4];
  int row = blockIdx.x, t = threadIdx.x;
  int id = ids[row], pid = pos[row], tt = tti[row];
  float v[3]; float s = 0.f;
  #pragma unroll
  for (int j = 0; j < 3; ++j) {
    int col = t + j * 256;
    v[j] = we[(size_t)id * E_ + col] + pe[(size_t)pid * E_ + col] + te[(size_t)tt * E_ + col];
    s += v[j];
  }
  float mean = blockAllSum<4>(s, tmp, t) * (1.f / E_);
  float ss = 0.f;
  #pragma unroll
  for (int j = 0; j < 3; ++j) { float d = v[j] - mean; ss += d * d; }
  float var = blockAllSum<4>(ss, tmp, t) * (1.f / E_);
  float rstd = rsqrtf(var + 1e-5f);
  float* op = x + (size_t)row * E_;
  ushort* ob = xb + (size_t)row * E_;
  #pragma unroll
  for (int j = 0; j < 3; ++j) {
    int col = t + j * 256;
    float o = (v[j] - mean) * rstd * g[col] + bb[col];
    op[col] = o;
    ob[col] = f2bf(o);
  }
}

// ---------------- fused partial-sum + bias + residual + LayerNorm ----------------
template<int NP>
__global__ __launch_bounds__(256) void ln_red_kernel(
    const float* yp, const float* bias, const float* res,
    const float* g, const float* bb, float* out, ushort* outb) {
  __shared__ float tmp[4];
  int row = blockIdx.x, t = threadIdx.x;
  const size_t MN = (size_t)B_ * S_ * E_;
  float v[3]; float s = 0.f;
  #pragma unroll
  for (int j = 0; j < 3; ++j) {
    int col = t + j * 256;
    float a = bias[col] + res[(size_t)row * E_ + col];
    #pragma unroll
    for (int p = 0; p < NP; ++p) a += yp[p * MN + (size_t)row * E_ + col];
    v[j] = a; s += a;
  }
  float mean = blockAllSum<4>(s, tmp, t) * (1.f / E_);
  float ss = 0.f;
  #pragma unroll
  for (int j = 0; j < 3; ++j) { float d = v[j] - mean; ss += d * d; }
  float var = blockAllSum<4>(ss, tmp, t) * (1.f / E_);
  float rstd = rsqrtf(var + 1e-5f);
  float* op = out + (size_t)row * E_;
  ushort* ob = outb + (size_t)row * E_;
  #pragma unroll
  for (int j = 0; j < 3; ++j) {
    int col = t + j * 256;
    float o = (v[j] - mean) * rstd * g[col] + bb[col];
    op[col] = o;
    ob[col] = f2bf(o);
  }
}

// ------------------------- weight transpose + bf16 convert -------------------------
// src fp32 [K][N] row-major -> dst bf16 [N][K]
__global__ __launch_bounds__(256) void transposeW_kernel(
    const float* __restrict__ src, ushort* __restrict__ dst, int K, int N) {
  __shared__ float tile[32][33];
  int k0 = blockIdx.y * 32, n0 = blockIdx.x * 32;
  int t = threadIdx.x;
  #pragma unroll
  for (int i = 0; i < 4; ++i) {
    int idx = t + i * 256; int r = idx >> 5, cc = idx & 31;
    tile[r][cc] = src[(size_t)(k0 + r) * N + n0 + cc];
  }
  __syncthreads();
  #pragma unroll
  for (int i = 0; i < 4; ++i) {
    int idx = t + i * 256; int r = idx >> 5, cc = idx & 31;
    dst[(size_t)(n0 + r) * K + k0 + cc] = f2bf(tile[cc][r]);
  }
}

// ------------------------- bf16 MFMA GEMM (2-phase double-buffered) -------------
// C[m,n] = A[m,:] . BT[n,:]. For the fused qkv|gkv GEMM, BT2 supplies rows
// n>=2304 at BT2[n-1536] (block-uniform select; 2304 is 128-aligned; BT2 is
// passed as WgT base so row n-1536 = Wg col (n-2304)+768) and bias2 supplies
// bias[n>=2304] at bias2[n-1536].
// EPI 0: bias -> bf16; EPI 1: bias+gelu -> bf16; EPI 3: fp32 split-K partial
template<int EPI>
__global__ __launch_bounds__(256) void gemm_mfma(
    const ushort* __restrict__ A, const ushort* __restrict__ BT,
    const ushort* __restrict__ BT2, const float* __restrict__ bias,
    const float* __restrict__ bias2,
    float* __restrict__ Cf, ushort* __restrict__ Cb, int M, int N, int K) {
  __shared__ __align__(16) ushort As[2][128 * 32];
  __shared__ __align__(16) ushort Bs[2][128 * 32];
  int t = threadIdx.x;
  int w = t >> 6, lane = t & 63;
  int wr = w >> 1, wc = w & 1;
  int fr = lane & 15, fg = lane >> 4;
  int m0 = blockIdx.y * 128, n0 = blockIdx.x * 128;
  int Kc = K / (int)gridDim.z;
  int kbeg = (int)blockIdx.z * Kc;
  const ushort* BTu = BT;
  int noff = n0;
  if (BT2 != nullptr && n0 >= 2304) { BTu = BT2; noff = n0 - 1536; }
  int lrow = lane >> 2, lcol = (lane & 3) * 8;

  f32x4 acc[4][4];
  #pragma unroll
  for (int m = 0; m < 4; ++m)
    #pragma unroll
    for (int n = 0; n < 4; ++n) acc[m][n] = (f32x4)0.f;

  auto stage = [&](int k0, int bsel) {
    #pragma unroll
    for (int j = 0; j < 2; ++j) {
      int rbase = w * 32 + j * 16;
      gload_lds16(A + (size_t)(m0 + rbase + lrow) * K + k0 + lcol,
                  (void*)(&As[bsel][rbase * 32]));
      gload_lds16(BTu + (size_t)(noff + rbase + lrow) * K + k0 + lcol,
                  (void*)(&Bs[bsel][rbase * 32]));
    }
  };

  int nkt = Kc / 32;
  stage(kbeg, 0);
  __syncthreads();
  for (int kt = 0; kt < nkt; ++kt) {
    int cur = kt & 1;
    if (kt + 1 < nkt) stage(kbeg + (kt + 1) * 32, cur ^ 1);   // prefetch next tile
    bf16x8 af[4], bf[4];
    #pragma unroll
    for (int m = 0; m < 4; ++m)
      af[m] = *(const bf16x8*)(&As[cur][(wr * 64 + m * 16 + fr) * 32 + fg * 8]);
    #pragma unroll
    for (int n = 0; n < 4; ++n)
      bf[n] = *(const bf16x8*)(&Bs[cur][(wc * 64 + n * 16 + fr) * 32 + fg * 8]);
    #pragma unroll
    for (int m = 0; m < 4; ++m)
      #pragma unroll
      for (int n = 0; n < 4; ++n)
        acc[m][n] = __builtin_amdgcn_mfma_f32_16x16x32_bf16(af[m], bf[n], acc[m][n], 0, 0, 0);
    __syncthreads();   // drains prefetch vmcnt + protects buffer reuse
  }

  #pragma unroll
  for (int n = 0; n < 4; ++n) {
    int col = n0 + wc * 64 + n * 16 + fr;
    float bv = 0.f;
    if (EPI != 3) bv = (bias2 != nullptr && col >= 2304) ? bias2[col - 1536] : bias[col];
    #pragma unroll
    for (int m = 0; m < 4; ++m) {
      int rbase = m0 + wr * 64 + m * 16 + fg * 4;
      #pragma unroll
      for (int r = 0; r < 4; ++r) {
        int row = rbase + r;
        float v = acc[m][n][r] + bv;
        if (EPI == 0) {
          Cb[(size_t)row * N + col] = f2bf(v);
        } else if (EPI == 1) {
          v = 0.5f * v * (1.f + erff(v * 0.70710678118654752f));
          Cb[(size_t)row * N + col] = f2bf(v);
        } else {
          Cf[(size_t)blockIdx.z * M * N + (size_t)row * N + col] = v;
        }
      }
    }
  }
}

// ------------------------- local sliding-window attention (MFMA, LDS-staged) ----
// One block = 4 waves = 64 queries of one (b,h). 9 key-tiles of 64 covering
// [qb0-256, qb0+320) (exact union of the queries' +/-256 windows); OOB tiles
// skipped block-uniformly. K staged [key][72], V staged transposed [d][72],
// P per-wave LDS; online softmax fp32; global key 0 folded into init.
#define PADK 72
__global__ __launch_bounds__(256) void attn_local_kernel(
    const ushort* __restrict__ qkv, const int* __restrict__ mask, ushort* __restrict__ aout) {
  __shared__ __align__(16) ushort Kb[64 * PADK];
  __shared__ __align__(16) ushort Vt[64 * PADK];
  __shared__ __align__(16) ushort Pl[4][16 * PADK];
  __shared__ float k0s[64], v0s[64];
  __shared__ float pen[64];
  int t = threadIdx.x;
  int w = t >> 6, lane = t & 63;
  int fr = lane & 15, fg = lane >> 4;
  int qb0 = blockIdx.x * 64;
  int h = blockIdx.y, b = blockIdx.z;
  const ushort* base = qkv + (size_t)b * S_ * QVS;
  const int* mrow = mask + b * S_;

  if (t < 64) k0s[t] = bf2f(base[768 + h * 64 + t]);
  else if (t < 128) v0s[t - 64] = bf2f(base[1536 + h * 64 + (t - 64)]);
  int gmask = mrow[0];

  // Q A-fragments, pre-scaled by 1/8 (exact pow2 scale)
  int qrowA = qb0 + w * 16 + fr;
  bf16x8 afq[2];
  #pragma unroll
  for (int kk = 0; kk < 2; ++kk) {
    u16x8 qv = *(const u16x8*)(base + (size_t)qrowA * QVS + h * 64 + kk * 32 + fg * 8);
    ushort o[8];
    #pragma unroll
    for (int j = 0; j < 8; ++j) o[j] = f2bf(bf2f(qv[j]) * 0.125f);
    afq[kk] = *(bf16x8*)o;
  }
  __syncthreads();

  // global key-0 score per A-row query, redistribute to C-row order
  float s0 = 0.f;
  #pragma unroll
  for (int kk = 0; kk < 2; ++kk) {
    ushort* ap = (ushort*)&afq[kk];
    #pragma unroll
    for (int j = 0; j < 8; ++j) s0 += bf2f(ap[j]) * k0s[kk * 32 + fg * 8 + j];
  }
  s0 += __shfl_xor(s0, 16, 64);
  s0 += __shfl_xor(s0, 32, 64);

  float m_j[4], l_j[4];
  f32x4 oa[4];       // O[q][d]: lane holds col d=dn*16+fr, rows q=fg*4+j
  #pragma unroll
  for (int j = 0; j < 4; ++j) {
    float s0q = __shfl(s0, fg * 4 + j, 64);
    m_j[j] = gmask ? s0q : -3.0e38f;
    l_j[j] = (gmask && fr == 0) ? 1.f : 0.f;
  }
  #pragma unroll
  for (int dn = 0; dn < 4; ++dn) {
    float v0 = gmask ? v0s[dn * 16 + fr] : 0.f;
    oa[dn] = (f32x4){v0, v0, v0, v0};
  }

  #pragma unroll 1
  for (int tile = 0; tile < 9; ++tile) {
    int r0 = qb0 - 256 + tile * 64;
    if (r0 < 0 || r0 >= S_) continue;      // block-uniform skip
    __syncthreads();
    {
      int kr = t >> 2, sg = t & 3;
      int kpos = r0 + kr;
      const ushort* kp = base + (size_t)kpos * QVS + 768 + h * 64 + sg * 16;
      u16x8 kv0 = *(const u16x8*)kp;
      u16x8 kv1 = *(const u16x8*)(kp + 8);
      const ushort* vp = kp + 768;
      u16x8 vv0 = *(const u16x8*)vp;
      u16x8 vv1 = *(const u16x8*)(vp + 8);
      *(u16x8*)(Kb + kr * PADK + sg * 16) = kv0;
      *(u16x8*)(Kb + kr * PADK + sg * 16 + 8) = kv1;
      #pragma unroll
      for (int dd = 0; dd < 8; ++dd) Vt[(sg * 16 + dd) * PADK + kr] = vv0[dd];
      #pragma unroll
      for (int dd = 0; dd < 8; ++dd) Vt[(sg * 16 + 8 + dd) * PADK + kr] = vv1[dd];
      if (sg == 0) pen[kr] = (kpos != 0 && mrow[kpos] == 1) ? 0.f : -1e9f;
    }
    __syncthreads();

    // scores: 16q x 64k
    f32x4 sc[4];
    #pragma unroll
    for (int kn = 0; kn < 4; ++kn) {
      bf16x8 bk0 = *(const bf16x8*)(Kb + (kn * 16 + fr) * PADK + fg * 8);
      bf16x8 bk1 = *(const bf16x8*)(Kb + (kn * 16 + fr) * PADK + 32 + fg * 8);
      f32x4 s = (f32x4)0.f;
      s = __builtin_amdgcn_mfma_f32_16x16x32_bf16(afq[0], bk0, s, 0, 0, 0);
      s = __builtin_amdgcn_mfma_f32_16x16x32_bf16(afq[1], bk1, s, 0, 0, 0);
      sc[kn] = s;
    }
    int qrowC = qb0 + w * 16 + fg * 4;
    #pragma unroll
    for (int kn = 0; kn < 4; ++kn) {
      int kpos = r0 + kn * 16 + fr;
      float pn = pen[kn * 16 + fr];
      #pragma unroll
      for (int j = 0; j < 4; ++j) {
        int dd = kpos - (qrowC + j);
        bool okr = (dd <= W_) && (dd >= -W_);
        sc[kn][j] = okr ? (sc[kn][j] + pn) : -1e9f;
      }
    }
    float f_j[4];
    #pragma unroll
    for (int j = 0; j < 4; ++j) {
      float tm = fmaxf(fmaxf(sc[0][j], sc[1][j]), fmaxf(sc[2][j], sc[3][j]));
      tm = fmaxf(tm, __shfl_xor(tm, 1, 64));
      tm = fmaxf(tm, __shfl_xor(tm, 2, 64));
      tm = fmaxf(tm, __shfl_xor(tm, 4, 64));
      tm = fmaxf(tm, __shfl_xor(tm, 8, 64));
      float mn = fmaxf(m_j[j], tm);
      float f = __expf(m_j[j] - mn);
      m_j[j] = mn;
      f_j[j] = f;
      l_j[j] *= f;
    }
    #pragma unroll
    for (int kn = 0; kn < 4; ++kn) {
      #pragma unroll
      for (int j = 0; j < 4; ++j) {
        float p = __expf(sc[kn][j] - m_j[j]);
        l_j[j] += p;
        Pl[w][(fg * 4 + j) * PADK + kn * 16 + fr] = f2bf(p);
      }
    }
    #pragma unroll
    for (int dn = 0; dn < 4; ++dn)
      #pragma unroll
      for (int j = 0; j < 4; ++j) oa[dn][j] *= f_j[j];
    // PV: O(16q x 64d) += P(16q x 64k) * V(64k x 64d)
    #pragma unroll
    for (int kk = 0; kk < 2; ++kk) {
      bf16x8 ap = *(const bf16x8*)(&Pl[w][fr * PADK + kk * 32 + fg * 8]);
      #pragma unroll
      for (int dn = 0; dn < 4; ++dn) {
        bf16x8 bv = *(const bf16x8*)(Vt + (dn * 16 + fr) * PADK + kk * 32 + fg * 8);
        oa[dn] = __builtin_amdgcn_mfma_f32_16x16x32_bf16(ap, bv, oa[dn], 0, 0, 0);
      }
    }
  }

  #pragma unroll
  for (int j = 0; j < 4; ++j) {
    float l = l_j[j];
    l += __shfl_xor(l, 1, 64);
    l += __shfl_xor(l, 2, 64);
    l += __shfl_xor(l, 4, 64);
    l += __shfl_xor(l, 8, 64);
    l_j[j] = 1.f / l;
  }
  __syncthreads();
  ushort* Ol = Kb;
  #pragma unroll
  for (int dn = 0; dn < 4; ++dn)
    #pragma unroll
    for (int j = 0; j < 4; ++j)
      Ol[(w * 16 + fg * 4 + j) * PADK + dn * 16 + fr] = f2bf(oa[dn][j] * l_j[j]);
  __syncthreads();
  {
    int q = t >> 2, sg = t & 3;
    int qpos = qb0 + q;
    u16x8 o0 = *(const u16x8*)(Ol + q * PADK + sg * 16);
    u16x8 o1 = *(const u16x8*)(Ol + q * PADK + sg * 16 + 8);
    ushort* op = aout + ((size_t)b * S_ + qpos) * E_ + h * 64 + sg * 16;
    *(u16x8*)op = o0;
    *(u16x8*)(op + 8) = o1;
  }
}

// ------------------- global attention for token 0 (split-s flash) ---------------
#define GSPLIT 8
__global__ __launch_bounds__(256) void attn_global_part(
    const float* __restrict__ qg0, const ushort* __restrict__ qgb,
    const int* __restrict__ mask, float* __restrict__ gws) {
  __shared__ float qs[64];
  __shared__ float ps[256];
  __shared__ float tmp[4];
  __shared__ float pacc[256];
  int h = blockIdx.x, b = blockIdx.y, c = blockIdx.z;
  int t = threadIdx.x;
  if (t < 16) *(float4*)&qs[t * 4] = *(const float4*)(qg0 + b * E_ + h * 64 + t * 4);
  __syncthreads();
  int s = c * 256 + t;
  const ushort* kr = qgb + ((size_t)b * S_ + s) * QVS + 2304 + h * 64;
  float sum = 0.f;
  #pragma unroll
  for (int d8 = 0; d8 < 8; ++d8) {
    u16x8 kv = *(const u16x8*)(kr + d8 * 8);
    #pragma unroll
    for (int j = 0; j < 8; ++j) sum += qs[d8 * 8 + j] * bf2f(kv[j]);
  }
  float sv = (mask[b * S_ + s] == 1) ? sum : -1e9f;
  float mc = blockAllMax<4>(sv, tmp, t);
  float p = __expf(sv - mc);
  ps[t] = p;
  float lc = blockAllSum<4>(p, tmp, t);
  __syncthreads();
  int d = t & 63, grp = t >> 6;
  float acc = 0.f;
  for (int i = 0; i < 64; ++i) {
    int sl = grp * 64 + i;
    acc += ps[sl] * bf2f(qgb[((size_t)b * S_ + c * 256 + sl) * QVS + 3072 + h * 64 + d]);
  }
  pacc[t] = acc;
  __syncthreads();
  float* gw = gws + ((size_t)(b * H_ + h) * GSPLIT + c) * 66;
  if (t < 64) gw[2 + t] = pacc[t] + pacc[t + 64] + pacc[t + 128] + pacc[t + 192];
  if (t == 0) { gw[0] = mc; gw[1] = lc; }
}

__global__ void attn_global_comb(const float* __restrict__ gws, ushort* __restrict__ aout) {
  int h = blockIdx.x, b = blockIdx.y, t = threadIdx.x;   // 64 threads
  const float* gw = gws + (size_t)(b * H_ + h) * GSPLIT * 66;
  float M = -3.0e38f;
  #pragma unroll
  for (int c = 0; c < GSPLIT; ++c) M = fmaxf(M, gw[c * 66]);
  float l = 0.f, o = 0.f;
  #pragma unroll
  for (int c = 0; c < GSPLIT; ++c) {
    float wgt = __expf(gw[c * 66] - M);
    l += wgt * gw[c * 66 + 1];
    o += wgt * gw[c * 66 + 2 + t];
  }
  aout[((size_t)b * S_) * E_ + h * 64 + t] = f2bf(o / l);
}

// ---------------- qg0[n] = (xb[b,0,:] . WgT[n,:] + bg[n]) / 8 -------------------
// one wave per output n; WgT rows are contiguous bf16.
__global__ __launch_bounds__(256) void qg0_kernel(
    const ushort* __restrict__ xb, const ushort* __restrict__ WgT,
    const float* __restrict__ bg, float* __restrict__ qg0) {
  int w = threadIdx.x >> 6, lane = threadIdx.x & 63;
  int n = blockIdx.x * 4 + w;
  int b = blockIdx.y;
  const ushort* xr = xb + (size_t)b * S_ * E_;
  const ushort* wr = WgT + (size_t)n * E_;
  float s = 0.f;
  #pragma unroll
  for (int j = 0; j < 12; ++j) {
    int k = lane * 12 + j;
    s += bf2f(xr[k]) * bf2f(wr[k]);
  }
  s = waveAllSum(s);
  if (lane == 0) qg0[b * E_ + n] = (s + bg[n]) * 0.125f;
}

// ------------------------- classification head -------------------------
__global__ void cls_kernel(const float* __restrict__ x, const float* __restrict__ cw,
                           const float* __restrict__ cb, float* __restrict__ cls) {
  int n = blockIdx.x * 256 + threadIdx.x;
  int b = blockIdx.y;
  const float* xr = x + (size_t)b * S_ * E_;
  float acc = cb[n];
  for (int k = 0; k < E_; ++k) acc += xr[k] * cw[(size_t)k * E_ + n];
  cls[b * E_ + n] = tanhf(acc);
}

__global__ void out_kernel(const float* __restrict__ cls, const float* __restrict__ ow,
                           const float* __restrict__ ob, float* __restrict__ out) {
  int t = threadIdx.x;
  if (t < B_ * NL_) {
    int b = t / NL_, n = t % NL_;
    float acc = ob[n];
    for (int k = 0; k < E_; ++k) acc += cls[b * E_ + k] * ow[(size_t)k * NL_ + n];
    out[t] = acc;
  }
}

// ------------------------- launch -------------------------
extern "C" void kernel_launch(void* const* d_in, const int* in_sizes, int n_in,
                              void* d_out, int out_size, void* d_ws, size_t ws_size,
                              hipStream_t stream) {
  const int* ids   = (const int*)d_in[0];
  const int* mask  = (const int*)d_in[1];
  const int* tti   = (const int*)d_in[2];
  const float* we  = (const float*)d_in[3];
  const float* pe  = (const float*)d_in[4];
  const float* te  = (const float*)d_in[5];
  const float* lng = (const float*)d_in[6];
  const float* lnb = (const float*)d_in[7];
  const float* Wqkv = (const float*)d_in[8];
  const float* bqkv = (const float*)d_in[9];
  const float* Wg   = (const float*)d_in[10];
  const float* bg   = (const float*)d_in[11];
  const float* Wo   = (const float*)d_in[12];
  const float* bo   = (const float*)d_in[13];
  const float* ln1g = (const float*)d_in[14];
  const float* ln1b = (const float*)d_in[15];
  const float* Wi   = (const float*)d_in[16];
  const float* bi   = (const float*)d_in[17];
  const float* Wf   = (const float*)d_in[18];
  const float* bf_  = (const float*)d_in[19];
  const float* ln2g = (const float*)d_in[20];
  const float* ln2b = (const float*)d_in[21];
  const float* cw   = (const float*)d_in[22];
  const float* cb   = (const float*)d_in[23];
  const float* ow   = (const float*)d_in[24];
  const float* ob   = (const float*)d_in[25];
  float* out = (float*)d_out;

  char* ws = (char*)d_ws;
  size_t off = 0;
  auto alloc = [&](size_t bytes) { void* p = ws + off; off += (bytes + 255) & ~(size_t)255; return p; };
  const size_t BSE = (size_t)B_ * S_ * E_;
  int*    pos  = (int*)alloc((size_t)B_ * S_ * 4);
  float*  x    = (float*)alloc(BSE * 4);
  ushort* xb   = (ushort*)alloc(BSE * 2);
  ushort* ab   = (ushort*)alloc(BSE * 2);
  ushort* qgb  = (ushort*)alloc((size_t)B_ * S_ * QVS * 2);   // fused qkv|gkv bf16
  float*  yp   = (float*)alloc(4 * BSE * 4);                  // split-K partials
  float*  qg0  = (float*)alloc((size_t)B_ * E_ * 4);
  float*  gws  = (float*)alloc((size_t)B_ * H_ * GSPLIT * 66 * 4);
  float*  cls  = (float*)alloc((size_t)B_ * E_ * 4);
  ushort* WqkvT = (ushort*)alloc((size_t)2304 * 768 * 2);
  ushort* WgT   = (ushort*)alloc((size_t)2304 * 768 * 2);
  ushort* WoT   = (ushort*)alloc((size_t)768 * 768 * 2);
  ushort* WiT   = (ushort*)alloc((size_t)3072 * 768 * 2);
  ushort* WfT   = (ushort*)alloc((size_t)768 * 3072 * 2);
  ushort* hb = qgb;   // FFN hidden (25.2MB bf16) aliases qgb (31.5MB, dead in FFN phase)

  const int M = B_ * S_;

  pos_ids_kernel<<<B_, 256, 0, stream>>>(mask, pos);
  embed_ln_kernel<<<M, 256, 0, stream>>>(ids, pos, tti, we, pe, te, lng, lnb, x, xb);

  for (int l = 0; l < L_; ++l) {
    const float* Wqkv_l = Wqkv + (size_t)l * E_ * 3 * E_;
    const float* bqkv_l = bqkv + (size_t)l * 3 * E_;
    const float* Wg_l   = Wg + (size_t)l * E_ * 3 * E_;
    const float* bg_l   = bg + (size_t)l * 3 * E_;
    const float* Wo_l   = Wo + (size_t)l * E_ * E_;
    const float* bo_l   = bo + (size_t)l * E_;
    const float* Wi_l   = Wi + (size_t)l * E_ * FF_;
    const float* bi_l   = bi + (size_t)l * FF_;
    const float* Wf_l   = Wf + (size_t)l * FF_ * E_;
    const float* bf_l   = bf_ + (size_t)l * E_;

    transposeW_kernel<<<dim3(2304 / 32, 768 / 32), 256, 0, stream>>>(Wqkv_l, WqkvT, 768, 2304);
    transposeW_kernel<<<dim3(2304 / 32, 768 / 32), 256, 0, stream>>>(Wg_l, WgT, 768, 2304);
    transposeW_kernel<<<dim3(768 / 32, 768 / 32), 256, 0, stream>>>(Wo_l, WoT, 768, 768);
    transposeW_kernel<<<dim3(3072 / 32, 768 / 32), 256, 0, stream>>>(Wi_l, WiT, 768, 3072);
    transposeW_kernel<<<dim3(768 / 32, 3072 / 32), 256, 0, stream>>>(Wf_l, WfT, 3072, 768);

    // fused [qkv | gkv] = x @ [Wqkv | Wg[:,E:]] + [bqkv | bg[E:]]  (bf16 out)
    // BT2 = WgT base: fused col n>=2304 reads WgT row n-1536 = Wg col (n-2304)+768
    gemm_mfma<0><<<dim3(QVS / 128, M / 128), 256, 0, stream>>>(
        xb, WqkvT, WgT, bqkv_l, bg_l, nullptr, qgb, M, QVS, 768);
    qg0_kernel<<<dim3(E_ / 4, B_), 256, 0, stream>>>(xb, WgT, bg_l, qg0);

    attn_local_kernel<<<dim3(S_ / 64, H_, B_), 256, 0, stream>>>(qgb, mask, ab);
    attn_global_part<<<dim3(H_, B_, GSPLIT), 256, 0, stream>>>(qg0, qgb, mask, gws);
    attn_global_comb<<<dim3(H_, B_), 64, 0, stream>>>(gws, ab);

    // Wo: split-K=2 partials, then fused reduce+bias+residual+LN
    gemm_mfma<3><<<dim3(768 / 128, M / 128, 2), 256, 0, stream>>>(
        ab, WoT, nullptr, nullptr, nullptr, yp, nullptr, M, 768, 768);
    ln_red_kernel<2><<<M, 256, 0, stream>>>(
        yp, bo_l, x, ln1g + (size_t)l * E_, ln1b + (size_t)l * E_, x, xb);

    // h = gelu(x @ Wi + bi) (bf16)
    gemm_mfma<1><<<dim3(3072 / 128, M / 128), 256, 0, stream>>>(
        xb, WiT, nullptr, bi_l, nullptr, nullptr, hb, M, 3072, 768);
    // Wf: split-K=4 partials, then fused reduce+bias+residual+LN
    gemm_mfma<3><<<dim3(768 / 128, M / 128, 4), 256, 0, stream>>>(
        hb, WfT, nullptr, nullptr, nullptr, yp, nullptr, M, 768, 3072);
    ln_red_kernel<4><<<M, 256, 0, stream>>>(
        yp, bf_l, x, ln2g + (size_t)l * E_, ln2b + (size_t)l * E_, x, xb);
  }

  cls_kernel<<<dim3(E_ / 256, B_), 256, 0, stream>>>(x, cw, cb, cls);
  out_kernel<<<1, 64, 0, stream>>>(cls, ow, ob, out);
}